// Round 13
// baseline (1457.066 us; speedup 1.0000x reference)
//
#include <hip/hip_runtime.h>
#include <hip/hip_bf16.h>

// ---------------- constants ----------------
constexpr int NN = 40000;   // nodes
constexpr int NE = 400000;  // edges (before self-loops)
constexpr int NSLAB = 20000;
constexpr int MPAD = 20096; // 157 * 128 (M-tile overrun padding)
constexpr int SCB = 256;    // scan blocks
constexpr int SCHUNK = (NN + SCB - 1) / SCB;   // 157 (<= 256)

__device__ __forceinline__ unsigned short f2bf(float f) {
    unsigned int u = __float_as_uint(f);
    unsigned int r = (u + 0x7FFFu + ((u >> 16) & 1u)) >> 16;
    return (unsigned short)r;
}

// async global->LDS 16B: no VGPR round-trip, loads issue back-to-back.
__device__ __forceinline__ void load_lds16(const unsigned short* g, unsigned short* l) {
    __builtin_amdgcn_global_load_lds(
        (const __attribute__((address_space(1))) unsigned int*)(g),
        (__attribute__((address_space(3))) unsigned int*)(l), 16, 0, 0);
}

typedef __attribute__((ext_vector_type(8))) short bf16x8;
typedef __attribute__((ext_vector_type(4))) float f32x4;
typedef __attribute__((ext_vector_type(2))) float floatx2;

// ---------------- BN ----------------
__global__ void bn_partial(const float* __restrict__ x, int N, int C,
                           float* __restrict__ partial) {
    int ch = threadIdx.x;            // blockDim = 128, C <= 128
    if (ch >= C) return;
    float s = 0.f, sq = 0.f;
    for (int n = blockIdx.x; n < N; n += gridDim.x) {
        float v = x[(size_t)n * C + ch];
        s += v; sq += v * v;
    }
    partial[(size_t)blockIdx.x * 2 * C + ch]     = s;
    partial[(size_t)blockIdx.x * 2 * C + C + ch] = sq;
}

__global__ void bn_finalize(const float* __restrict__ partial, int nb, int C, float fN,
                            const float* __restrict__ g, const float* __restrict__ be,
                            float* __restrict__ scale, float* __restrict__ shift) {
    int ch = threadIdx.x;
    if (ch >= C) return;
    float s = 0.f, sq = 0.f;
    for (int b = 0; b < nb; ++b) {
        s  += partial[(size_t)b * 2 * C + ch];
        sq += partial[(size_t)b * 2 * C + C + ch];
    }
    float mean = s / fN;
    float var  = sq / fN - mean * mean;
    float inv  = rsqrtf(var + 1e-5f);
    float sc   = g[ch] * inv;
    scale[ch] = sc;
    shift[ch] = be[ch] - mean * sc;
}

// xbn[n, c] (bf16, stride CP, zero-padded c>=CIN) = scale*x+shift
template <int CIN, int CP>
__global__ void bn_apply(const float* __restrict__ x, const float* __restrict__ scale,
                         const float* __restrict__ shift, unsigned short* __restrict__ xbn) {
    int idx = blockIdx.x * blockDim.x + threadIdx.x;
    if (idx >= NN * CP) return;
    int n = idx / CP, c = idx % CP;
    float v = 0.f;
    if (c < CIN) v = scale[c] * x[(size_t)n * CIN + c] + shift[c];
    xbn[idx] = f2bf(v);
}

// ---------------- fold a_src/a_dst into W:  Wf[cin, j]  +  bf16 Wft[j][CP] ----------
__global__ void fold_kernel(const float* __restrict__ W, const float* __restrict__ as_,
                            const float* __restrict__ ad_, int C, int CP,
                            float* __restrict__ Wf, unsigned short* __restrict__ Wft) {
    int cin = blockIdx.x;
    int j = threadIdx.x;             // 64
    int h = j & 31;
    const float* a = (j < 32) ? as_ : ad_;
    const float* wrow = W + (size_t)cin * 32 * C + (size_t)h * C;
    const float* arow = a + (size_t)h * C;
    float s = 0.f;
    for (int c = 0; c < C; ++c) s += wrow[c] * arow[c];
    Wf[cin * 64 + j] = s;
    Wft[j * CP + cin] = f2bf(s);
}

// Wt[c][h*CP + k] = W[k][h*COUT + c] / 32  (bf16, zero-padded), c in [0,NP)
__global__ void repack_w(const float* __restrict__ W, int CIN, int CP, int COUT,
                         unsigned short* __restrict__ Wt) {
    int c = blockIdx.x;              // [0, NP)
    for (int kk = threadIdx.x; kk < 32 * CP; kk += blockDim.x) {
        int h = kk / CP, k = kk % CP;
        float v = 0.f;
        if (c < COUT && k < CIN) v = W[(size_t)k * (32 * COUT) + h * COUT + c] * (1.f / 32.f);
        Wt[(size_t)c * (32 * CP) + kk] = f2bf(v);
    }
}

// Wtp[k][16] = W[kk][h*COUT+c]/32 where k = h*CP+kk (bf16, zero-padded) — for fused proj
__global__ void repack_wp(const float* __restrict__ W, int CIN, int CP, int COUT,
                          unsigned short* __restrict__ Wtp) {
    int idx = blockIdx.x * blockDim.x + threadIdx.x;
    if (idx >= 32 * CP * 16) return;
    int k = idx >> 4, c = idx & 15;
    int h = k / CP, kk = k % CP;
    float v = 0.f;
    if (kk < CIN && c < COUT) v = W[(size_t)kk * (32 * COUT) + h * COUT + c] * (1.f / 32.f);
    Wtp[idx] = f2bf(v);
}

// ---------------- MFMA score GEMM: Sbuf[n, 0:64] = xbn[n,:] @ Wft^T ------------------
template <int KP>
__global__ __launch_bounds__(256) void gemm_s(const unsigned short* __restrict__ xbn,
                                              const unsigned short* __restrict__ Wft,
                                              float* __restrict__ Sbuf) {
    constexpr int NC = KP / 32;
    __shared__ unsigned short Ab[64 * 32];
    __shared__ unsigned short Bb[64 * 32];
    const int m0 = blockIdx.x * 64;
    const int tid = threadIdx.x;
    const int wv = tid >> 6, lane = tid & 63;
    const int mm = lane & 15, quad = lane >> 4;
    f32x4 acc[4];
#pragma unroll
    for (int t = 0; t < 4; ++t) acc[t] = f32x4{0.f, 0.f, 0.f, 0.f};

    for (int c = 0; c < NC; ++c) {
        int row = tid >> 2, gc = tid & 3;
        load_lds16(xbn + (size_t)(m0 + row) * KP + c * 32 + gc * 8, Ab + (size_t)tid * 8);
        load_lds16(Wft + (size_t)row * KP + c * 32 + gc * 8, Bb + (size_t)tid * 8);
        asm volatile("s_waitcnt vmcnt(0)" ::: "memory");
        __syncthreads();
        bf16x8 a = *reinterpret_cast<const bf16x8*>(&Ab[(wv * 16 + mm) * 32 + quad * 8]);
#pragma unroll
        for (int t = 0; t < 4; ++t) {
            bf16x8 b = *reinterpret_cast<const bf16x8*>(&Bb[(t * 16 + mm) * 32 + quad * 8]);
            acc[t] = __builtin_amdgcn_mfma_f32_16x16x32_bf16(a, b, acc[t], 0, 0, 0);
        }
        __syncthreads();
    }
    int rbase = m0 + wv * 16 + quad * 4;
#pragma unroll
    for (int t = 0; t < 4; ++t)
#pragma unroll
        for (int r = 0; r < 4; ++r)
            Sbuf[(size_t)(rbase + r) * 64 + t * 16 + mm] = acc[t][r];
}

// ---------------- fp32 GEMM with fused BN on A (score GEMM for small-K layers) ----
__global__ __launch_bounds__(256) void gemm_bn(const float* __restrict__ X,
                                               const float* __restrict__ W,
                                               const float* __restrict__ scale,
                                               const float* __restrict__ shift,
                                               int Cin, int HC, float* __restrict__ OUT) {
    __shared__ float As[8][64];
    __shared__ float Bs[8][64];
    int tid = threadIdx.x;
    int n0 = blockIdx.y * 64;
    int j0 = blockIdx.x * 64;
    int tr = tid >> 4, tc = tid & 15;
    float acc[4][4] = {};
    for (int k0 = 0; k0 < Cin; k0 += 8) {
        int idx = tid;
#pragma unroll
        for (int it = 0; it < 2; ++it, idx += 256) {
            int row = idx >> 3, kk = idx & 7;
            int k = k0 + kk;
            float v = 0.f;
            if (k < Cin) v = scale[k] * X[(size_t)(n0 + row) * Cin + k] + shift[k];
            As[kk][row] = v;
        }
        int idx2 = tid;
#pragma unroll
        for (int it = 0; it < 2; ++it, idx2 += 256) {
            int col = idx2 & 63, kr = idx2 >> 6;
            int k = k0 + kr, j = j0 + col;
            float v = 0.f;
            if (k < Cin && j < HC) v = W[(size_t)k * HC + j];
            Bs[kr][col] = v;
        }
        __syncthreads();
#pragma unroll
        for (int kk = 0; kk < 8; ++kk) {
            float a[4], b[4];
#pragma unroll
            for (int i = 0; i < 4; ++i) a[i] = As[kk][tr * 4 + i];
#pragma unroll
            for (int j = 0; j < 4; ++j) b[j] = Bs[kk][tc * 4 + j];
#pragma unroll
            for (int i = 0; i < 4; ++i)
#pragma unroll
                for (int j = 0; j < 4; ++j) acc[i][j] += a[i] * b[j];
        }
        __syncthreads();
    }
#pragma unroll
    for (int i = 0; i < 4; ++i) {
        int row = n0 + tr * 4 + i;
#pragma unroll
        for (int j = 0; j < 4; ++j) {
            int col = j0 + tc * 4 + j;
            if (col < HC) OUT[(size_t)row * HC + col] = acc[i][j];
        }
    }
}

// ---------------- CSR build (hierarchical 3-pass scan) ----------------
__global__ void deg_init(int* __restrict__ deg) {
    int n = blockIdx.x * blockDim.x + threadIdx.x;
    if (n < NN) deg[n] = 1;   // self-loop
}
__global__ void count_kernel(const int* __restrict__ dst, int* __restrict__ deg) {
    int e = blockIdx.x * blockDim.x + threadIdx.x;
    if (e < NE) atomicAdd(&deg[dst[e]], 1);
}
__global__ void scan_pass1(const int* __restrict__ deg, int* __restrict__ bsum) {
    __shared__ int red[256];
    int b = blockIdx.x, t = threadIdx.x;
    int lo = b * SCHUNK, hi = min(lo + SCHUNK, NN);
    int s = 0;
    for (int i = lo + t; i < hi; i += 256) s += deg[i];
    red[t] = s;
    __syncthreads();
    for (int off = 128; off > 0; off >>= 1) {
        if (t < off) red[t] += red[t + off];
        __syncthreads();
    }
    if (t == 0) bsum[b] = red[0];
}
__global__ void scan_pass2(const int* __restrict__ bsum, int* __restrict__ boff,
                           int* __restrict__ rowptr) {
    __shared__ int lds[256];
    int t = threadIdx.x;
    int v0 = bsum[t];
    lds[t] = v0;
    __syncthreads();
    for (int off = 1; off < 256; off <<= 1) {
        int v = (t >= off) ? lds[t - off] : 0;
        __syncthreads();
        lds[t] += v;
        __syncthreads();
    }
    boff[t] = lds[t] - v0;          // exclusive
    if (t == 255) rowptr[NN] = lds[255];
}
__global__ void scan_pass3(const int* __restrict__ deg, const int* __restrict__ boff,
                           int* __restrict__ rowptr, int* __restrict__ cursor) {
    __shared__ int lds[256];
    int b = blockIdx.x, t = threadIdx.x;
    int i = b * SCHUNK + t;
    int d = (t < SCHUNK && i < NN) ? deg[i] : 0;
    lds[t] = d;
    __syncthreads();
    for (int off = 1; off < 256; off <<= 1) {
        int v = (t >= off) ? lds[t - off] : 0;
        __syncthreads();
        lds[t] += v;
        __syncthreads();
    }
    if (t < SCHUNK && i < NN) {
        int excl = lds[t] - d + boff[b];
        rowptr[i] = excl;
        cursor[i] = excl;
    }
}
__global__ void scatter_edges(const int* __restrict__ src, const int* __restrict__ dst,
                              int* __restrict__ cursor, int* __restrict__ colsrc) {
    int e = blockIdx.x * blockDim.x + threadIdx.x;
    if (e < NE) {
        int pos = atomicAdd(&cursor[dst[e]], 1);
        colsrc[pos] = src[e];
    }
}
__global__ void scatter_self(int* __restrict__ cursor, int* __restrict__ colsrc) {
    int n = blockIdx.x * blockDim.x + threadIdx.x;
    if (n < NN) {
        int pos = atomicAdd(&cursor[n], 1);
        colsrc[pos] = n;
    }
}

// ---------------- pass A: softmax-aggregate xbn -> z[n, 32*CP] (bf16) — L1/L2 ------
template <int CIN, int CP>
__global__ __launch_bounds__(256) void agg_x(const unsigned short* __restrict__ xbn,
                                             const float* __restrict__ S,
                                             const int* __restrict__ rowptr,
                                             const int* __restrict__ colsrc,
                                             int n0, unsigned short* __restrict__ z) {
    constexpr int BS = 256, CH = 32, J = CP / 8;   // J = 16,12
    constexpr bool V4 = (J % 4 == 0);
    constexpr int NACC = V4 ? (J / 4) : (J / 2);
    __shared__ float x_lds[CH * CP];
    __shared__ float w_lds[CH * 32];
    __shared__ int cs_lds[CH];
    __shared__ float sdst[32], m_lds[32], d_lds[32], r_lds[32];
    __shared__ float red[8][32];

    int n = n0 + blockIdx.x;
    int tid = threadIdx.x;
    int start = rowptr[n], end = rowptr[n + 1];
    if (tid < 32) {
        sdst[tid] = S[(size_t)n * 64 + 32 + tid];
        m_lds[tid] = -INFINITY;
        d_lds[tid] = 0.f;
    }
    const int h = tid & 31, g = tid >> 5;
    const int cbase = g * J;
    f32x4 acc4[V4 ? NACC : 1];
    floatx2 acc2[V4 ? 1 : NACC];
    if constexpr (V4) {
#pragma unroll
        for (int j = 0; j < NACC; ++j) acc4[j] = f32x4{0.f, 0.f, 0.f, 0.f};
    } else {
#pragma unroll
        for (int j = 0; j < NACC; ++j) acc2[j] = floatx2{0.f, 0.f};
    }

    for (int chunk = start; chunk < end; chunk += CH) {
        int ce = min(CH, end - chunk);
        int ce32 = ce * 32;
        if (tid < 32 && tid < ce) cs_lds[tid] = colsrc[chunk + tid];
        __syncthreads();

        float lreg[4];
        float pmx = -INFINITY;
#pragma unroll
        for (int p = 0; p < 4; ++p) {
            int idx = p * 256 + tid;
            lreg[p] = -INFINITY;
            if (idx < ce32) {
                int e = idx >> 5;
                float l = S[(size_t)cs_lds[e] * 64 + h] + sdst[h];
                l = l > 0.f ? l : 0.2f * l;
                lreg[p] = l;
                pmx = fmaxf(pmx, l);
            }
        }
        red[g][h] = pmx;
        for (int idx = tid; idx < ce * (CP / 2); idx += BS) {
            int e = idx / (CP / 2), c2 = idx % (CP / 2);
            unsigned int u =
                reinterpret_cast<const unsigned int*>(xbn)[(size_t)cs_lds[e] * (CP / 2) + c2];
            x_lds[e * CP + 2 * c2]     = __uint_as_float(u << 16);
            x_lds[e * CP + 2 * c2 + 1] = __uint_as_float(u & 0xFFFF0000u);
        }
        __syncthreads();
        if (tid < 32) {
            float cm = red[0][tid];
#pragma unroll
            for (int s2 = 1; s2 < 8; ++s2) cm = fmaxf(cm, red[s2][tid]);
            float oldm = m_lds[tid], newm = fmaxf(oldm, cm);
            r_lds[tid] = (oldm == -INFINITY) ? 0.f : __expf(oldm - newm);
            m_lds[tid] = newm;
        }
        __syncthreads();
        {
            float mh = m_lds[h];
            float ps = 0.f;
#pragma unroll
            for (int p = 0; p < 4; ++p) {
                int idx = p * 256 + tid;
                if (idx < ce32) {
                    float v = __expf(lreg[p] - mh);
                    w_lds[idx] = v;
                    ps += v;
                }
            }
            red[g][h] = ps;
        }
        __syncthreads();
        if (tid < 32) {
            float ss = 0.f;
#pragma unroll
            for (int s2 = 0; s2 < 8; ++s2) ss += red[s2][tid];
            d_lds[tid] = d_lds[tid] * r_lds[tid] + ss;
        }
        float rr = r_lds[h];
        if constexpr (V4) {
            f32x4 rr4 = {rr, rr, rr, rr};
#pragma unroll
            for (int j = 0; j < NACC; ++j) acc4[j] *= rr4;
            for (int e = 0; e < ce; ++e) {
                float w = w_lds[e * 32 + h];
                f32x4 w4 = {w, w, w, w};
                const f32x4* xv = reinterpret_cast<const f32x4*>(&x_lds[e * CP + cbase]);
#pragma unroll
                for (int j = 0; j < NACC; ++j) acc4[j] += w4 * xv[j];
            }
        } else {
            floatx2 rr2 = {rr, rr};
#pragma unroll
            for (int j = 0; j < NACC; ++j) acc2[j] *= rr2;
            for (int e = 0; e < ce; ++e) {
                float w = w_lds[e * 32 + h];
                floatx2 w2 = {w, w};
                const floatx2* xv = reinterpret_cast<const floatx2*>(&x_lds[e * CP + cbase]);
#pragma unroll
                for (int j = 0; j < NACC; ++j) acc2[j] += w2 * xv[j];
            }
        }
    }
    __syncthreads();
    float dinv = 1.f / d_lds[h];
    unsigned int* zp = reinterpret_cast<unsigned int*>(
        z + (size_t)(n - n0) * (32 * CP) + h * CP + cbase);
    if constexpr (V4) {
#pragma unroll
        for (int j = 0; j < NACC; ++j) {
            zp[2 * j]     = (unsigned int)f2bf(acc4[j][0] * dinv)
                          | ((unsigned int)f2bf(acc4[j][1] * dinv) << 16);
            zp[2 * j + 1] = (unsigned int)f2bf(acc4[j][2] * dinv)
                          | ((unsigned int)f2bf(acc4[j][3] * dinv) << 16);
        }
    } else {
#pragma unroll
        for (int j = 0; j < NACC; ++j) {
            zp[j] = (unsigned int)f2bf(acc2[j][0] * dinv)
                  | ((unsigned int)f2bf(acc2[j][1] * dinv) << 16);
        }
    }
}

// ---------------- fused agg + projection — L3/L4 (Wtp small) ----------------
// Round-12: z round-trip dominated traffic. For small layers the projection weight
// (KP x 16 bf16) is <=48 KB, so project in-block: stage normalized z (fp32) into
// x_lds (CH*CP == KP floats), sliced dot-product vs Wtp[k][16], bias+leaky, write
// xout directly. Removes z write/read, gemm_z_t, reduce for L3/L4.
template <int CIN, int CP, int COUT>
__global__ __launch_bounds__(256) void agg_proj(const unsigned short* __restrict__ xbn,
                                                const float* __restrict__ S,
                                                const int* __restrict__ rowptr,
                                                const int* __restrict__ colsrc,
                                                const unsigned short* __restrict__ Wtp,
                                                const float* __restrict__ bias,
                                                float* __restrict__ xout) {
    constexpr int BS = 256, CH = 32, J = CP / 8;   // J = 6, 2
    constexpr int NACC = J / 2;
    constexpr int KP = 32 * CP;
    constexpr int SL = KP / 16;
    __shared__ float x_lds[CH * CP];   // also zf[KP] in epilogue (same size)
    __shared__ float w_lds[CH * 32];   // also proj reduction scratch (256 floats)
    __shared__ int cs_lds[CH];
    __shared__ float sdst[32], m_lds[32], d_lds[32], r_lds[32];
    __shared__ float red[8][32];

    int n = blockIdx.x + (int)blockIdx.y * NSLAB;
    int tid = threadIdx.x;
    int start = rowptr[n], end = rowptr[n + 1];
    if (tid < 32) {
        sdst[tid] = S[(size_t)n * 64 + 32 + tid];
        m_lds[tid] = -INFINITY;
        d_lds[tid] = 0.f;
    }
    const int h = tid & 31, g = tid >> 5;
    const int cbase = g * J;
    floatx2 acc2[NACC];
#pragma unroll
    for (int j = 0; j < NACC; ++j) acc2[j] = floatx2{0.f, 0.f};

    for (int chunk = start; chunk < end; chunk += CH) {
        int ce = min(CH, end - chunk);
        int ce32 = ce * 32;
        if (tid < 32 && tid < ce) cs_lds[tid] = colsrc[chunk + tid];
        __syncthreads();

        float lreg[4];
        float pmx = -INFINITY;
#pragma unroll
        for (int p = 0; p < 4; ++p) {
            int idx = p * 256 + tid;
            lreg[p] = -INFINITY;
            if (idx < ce32) {
                int e = idx >> 5;
                float l = S[(size_t)cs_lds[e] * 64 + h] + sdst[h];
                l = l > 0.f ? l : 0.2f * l;
                lreg[p] = l;
                pmx = fmaxf(pmx, l);
            }
        }
        red[g][h] = pmx;
        for (int idx = tid; idx < ce * (CP / 2); idx += BS) {
            int e = idx / (CP / 2), c2 = idx % (CP / 2);
            unsigned int u =
                reinterpret_cast<const unsigned int*>(xbn)[(size_t)cs_lds[e] * (CP / 2) + c2];
            x_lds[e * CP + 2 * c2]     = __uint_as_float(u << 16);
            x_lds[e * CP + 2 * c2 + 1] = __uint_as_float(u & 0xFFFF0000u);
        }
        __syncthreads();
        if (tid < 32) {
            float cm = red[0][tid];
#pragma unroll
            for (int s2 = 1; s2 < 8; ++s2) cm = fmaxf(cm, red[s2][tid]);
            float oldm = m_lds[tid], newm = fmaxf(oldm, cm);
            r_lds[tid] = (oldm == -INFINITY) ? 0.f : __expf(oldm - newm);
            m_lds[tid] = newm;
        }
        __syncthreads();
        {
            float mh = m_lds[h];
            float ps = 0.f;
#pragma unroll
            for (int p = 0; p < 4; ++p) {
                int idx = p * 256 + tid;
                if (idx < ce32) {
                    float v = __expf(lreg[p] - mh);
                    w_lds[idx] = v;
                    ps += v;
                }
            }
            red[g][h] = ps;
        }
        __syncthreads();
        if (tid < 32) {
            float ss = 0.f;
#pragma unroll
            for (int s2 = 0; s2 < 8; ++s2) ss += red[s2][tid];
            d_lds[tid] = d_lds[tid] * r_lds[tid] + ss;
        }
        float rr = r_lds[h];
        floatx2 rr2 = {rr, rr};
#pragma unroll
        for (int j = 0; j < NACC; ++j) acc2[j] *= rr2;
        for (int e = 0; e < ce; ++e) {
            float w = w_lds[e * 32 + h];
            floatx2 w2 = {w, w};
            const floatx2* xv = reinterpret_cast<const floatx2*>(&x_lds[e * CP + cbase]);
#pragma unroll
            for (int j = 0; j < NACC; ++j) acc2[j] += w2 * xv[j];
        }
    }
    __syncthreads();          // accumulate done; x_lds reusable as zf
    if (tid < 32) r_lds[tid] = 1.f / d_lds[tid];
    __syncthreads();
    float dinv = r_lds[h];
    float* zf = x_lds;
#pragma unroll
    for (int j = 0; j < NACC; ++j) {
        zf[h * CP + cbase + 2 * j]     = acc2[j][0] * dinv;
        zf[h * CP + cbase + 2 * j + 1] = acc2[j][1] * dinv;
    }
    __syncthreads();
    // projection: out[c] = sum_k zf[k] * Wtp[k*16+c]; 16 slices x 16 c
    {
        const int c = tid & 15, s = tid >> 4;
        const unsigned short* wp = Wtp + (size_t)(s * SL) * 16 + c;
        const float* zp = zf + s * SL;
        float part = 0.f;
#pragma unroll 8
        for (int k = 0; k < SL; ++k) {
            float wv = __uint_as_float((unsigned int)wp[k * 16] << 16);
            part += zp[k] * wv;
        }
        w_lds[tid] = part;
    }
    __syncthreads();
    if (tid < COUT) {
        float sum = 0.f;
#pragma unroll
        for (int s2 = 0; s2 < 16; ++s2) sum += w_lds[s2 * 16 + tid];
        float v = sum + bias[tid];
        v = v > 0.f ? v : 0.01f * v;
        xout[(size_t)n * COUT + tid] = v;
    }
}

// ---------------- pass B: LDS-tiled MFMA GEMM, atomic K-split ----------------
// Round-12: 4-part pbuf materialization (write 31 MB + read 31 MB per L1 slab)
// replaced by atomicAdd into a zeroed fp32 buffer (4 spread writers/address).
template <int NT, int KP, int KS>
__global__ __launch_bounds__(256) void gemm_z_t(const unsigned short* __restrict__ z,
                                                const unsigned short* __restrict__ Wt,
                                                float* __restrict__ obuf) {
    constexpr int NP = NT * 16;
    constexpr int KSEG = KP / KS;       // multiple of 64
    constexpr int NC = KSEG / 64;
    constexpr int MT = 128;
    __shared__ unsigned short Abuf[2][MT * 64];
    __shared__ unsigned short Bbuf[2][NP * 64];

    const int m0 = blockIdx.x * MT;
    const int kbeg = blockIdx.y * KSEG;
    const int tid = threadIdx.x;
    const int wv = tid >> 6;
    const int lane = tid & 63;
    const int mm = lane & 15, quad = lane >> 4;

    auto stage = [&](int buf, int kk) {
#pragma unroll
        for (int it = 0; it < 4; ++it) {
            int gi = it * 256 + tid;
            int row = gi >> 3, gc = gi & 7;
            int srow = m0 + row;
            if (srow > NSLAB - 1) srow = NSLAB - 1;
            const unsigned short* src = z + (size_t)srow * KP + kk + gc * 8;
            unsigned short* dst = &Abuf[buf][(size_t)(it * 256 + wv * 64) * 8];
            load_lds16(src, dst);
        }
#pragma unroll
        for (int it = 0; it < (NP * 8 + 255) / 256; ++it) {
            int gi = it * 256 + tid;
            if (gi < NP * 8) {
                int row = gi >> 3, gc = gi & 7;
                const unsigned short* src = Wt + (size_t)row * KP + kk + gc * 8;
                unsigned short* dst = &Bbuf[buf][(size_t)(it * 256 + wv * 64) * 8];
                load_lds16(src, dst);
            }
        }
    };

    f32x4 acc[2][NT];
#pragma unroll
    for (int f = 0; f < 2; ++f)
#pragma unroll
        for (int t = 0; t < NT; ++t) acc[f][t] = f32x4{0.f, 0.f, 0.f, 0.f};

    stage(0, kbeg);
    for (int c = 0; c < NC; ++c) {
        asm volatile("s_waitcnt vmcnt(0)" ::: "memory");
        __syncthreads();
        int cur = c & 1;
        if (c + 1 < NC) stage(cur ^ 1, kbeg + (c + 1) * 64);
        const unsigned short* Ab = Abuf[cur];
        const unsigned short* Bb = Bbuf[cur];
#pragma unroll
        for (int hh = 0; hh < 2; ++hh) {
            bf16x8 a0 = *reinterpret_cast<const bf16x8*>(&Ab[(wv * 32 + mm) * 64 + hh * 32 + quad * 8]);
            bf16x8 a1 = *reinterpret_cast<const bf16x8*>(&Ab[(wv * 32 + 16 + mm) * 64 + hh * 32 + quad * 8]);
#pragma unroll
            for (int t = 0; t < NT; ++t) {
                bf16x8 b = *reinterpret_cast<const bf16x8*>(&Bb[(t * 16 + mm) * 64 + hh * 32 + quad * 8]);
                acc[0][t] = __builtin_amdgcn_mfma_f32_16x16x32_bf16(a0, b, acc[0][t], 0, 0, 0);
                acc[1][t] = __builtin_amdgcn_mfma_f32_16x16x32_bf16(a1, b, acc[1][t], 0, 0, 0);
            }
        }
        __syncthreads();
    }

    int row0 = quad * 4;
#pragma unroll
    for (int f = 0; f < 2; ++f) {
#pragma unroll
        for (int t = 0; t < NT; ++t) {
            int cc = t * 16 + mm;
#pragma unroll
            for (int r = 0; r < 4; ++r) {
                int m = m0 + wv * 32 + f * 16 + row0 + r;
                if (m < NSLAB) atomicAdd(&obuf[(size_t)m * NP + cc], acc[f][t][r]);
            }
        }
    }
}

// bias + leaky 0.01 -> xout
__global__ void bias_leaky(const float* __restrict__ obuf, int NPAD, int COUT,
                           const float* __restrict__ bias, int n0,
                           float* __restrict__ xout) {
    int idx = blockIdx.x * blockDim.x + threadIdx.x;
    if (idx >= NSLAB * NPAD) return;
    int m = idx / NPAD, c = idx % NPAD;
    if (c >= COUT) return;
    float v = obuf[idx] + bias[c];
    v = v > 0.f ? v : 0.01f * v;
    xout[(size_t)(n0 + m) * COUT + c] = v;
}

// ---------------- fused mean-pool + FC + sigmoid ----------------
__global__ __launch_bounds__(64) void pool_head(const float* __restrict__ x4,
                                                const int* __restrict__ batch,
                                                const float* __restrict__ cond,
                                                const float* __restrict__ fcW,
                                                const float* __restrict__ fcb,
                                                float* __restrict__ out) {
    int g = blockIdx.x;
    int lane = threadIdx.x;
    int lo = 0, hi = NN;
    while (lo < hi) { int mid = (lo + hi) >> 1; if (batch[mid] < g) lo = mid + 1; else hi = mid; }
    int lo2 = lo, hi2 = NN;
    while (lo2 < hi2) { int mid = (lo2 + hi2) >> 1; if (batch[mid] < g + 1) lo2 = mid + 1; else hi2 = mid; }
    int beg = lo, end = lo2;

    float s[5] = {0.f, 0.f, 0.f, 0.f, 0.f};
    for (int n = beg + lane; n < end; n += 64) {
#pragma unroll
        for (int c = 0; c < 5; ++c) s[c] += x4[(size_t)n * 5 + c];
    }
    float cz = 0.f;
    if (lane < 100) cz = cond[lane] * fcW[5 + lane];
    if (lane + 64 < 100) cz += cond[lane + 64] * fcW[5 + lane + 64];
#pragma unroll
    for (int off = 32; off > 0; off >>= 1) {
#pragma unroll
        for (int c = 0; c < 5; ++c) s[c] += __shfl_down(s[c], off, 64);
        cz += __shfl_down(cz, off, 64);
    }
    if (lane == 0) {
        float cnt = fmaxf((float)(end - beg), 1.f);
        float zv = fcb[0] + cz;
#pragma unroll
        for (int c = 0; c < 5; ++c) zv += (s[c] / cnt) * fcW[c];
        out[g] = 1.f / (1.f + __expf(-zv));
    }
}

// ---------------- per-layer driver ----------------
struct LayerBufs {
    float* partial; float* scale; float* shift; float* Wf;
    unsigned short* Wft;
    unsigned short* xbn; unsigned short* Wt; unsigned short* zbuf;
    float* Sbuf; float* pbuf; const int* rowptr; const int* colsrc;
};

template <int CIN, int CP, int COUT, int NP, int NT, int KS>
static void run_layer(const float* xin, const float* W, const float* As_, const float* Ad_,
                      const float* Bv, const float* G, const float* Be,
                      float* xout, const LayerBufs& B, hipStream_t stream) {
    constexpr int KP = 32 * CP;
    constexpr int NPAD = NT * 16;
    bn_partial<<<256, 128, 0, stream>>>(xin, NN, CIN, B.partial);
    bn_finalize<<<1, 128, 0, stream>>>(B.partial, 256, CIN, (float)NN, G, Be, B.scale, B.shift);
    bn_apply<CIN, CP><<<(NN * CP + 255) / 256, 256, 0, stream>>>(xin, B.scale, B.shift, B.xbn);
    if constexpr (CP >= 64) {
        hipMemsetAsync(B.Wft, 0, (size_t)64 * CP * 2, stream);
        fold_kernel<<<CIN, 64, 0, stream>>>(W, As_, Ad_, COUT, CP, B.Wf, B.Wft);
        gemm_s<CP><<<NN / 64, 256, 0, stream>>>(B.xbn, B.Wft, B.Sbuf);
        repack_w<<<NP, 256, 0, stream>>>(W, CIN, CP, COUT, B.Wt);
        for (int s = 0; s < 2; ++s) {
            int n0 = s * NSLAB;
            hipMemsetAsync(B.pbuf, 0, (size_t)NSLAB * NPAD * 4, stream);
            agg_x<CIN, CP><<<NSLAB, 256, 0, stream>>>(B.xbn, B.Sbuf, B.rowptr, B.colsrc, n0, B.zbuf);
            gemm_z_t<NT, KP, KS><<<dim3(MPAD / 128, KS), 256, 0, stream>>>(B.zbuf, B.Wt, B.pbuf);
            bias_leaky<<<(NSLAB * NPAD + 255) / 256, 256, 0, stream>>>(
                B.pbuf, NPAD, COUT, Bv, n0, xout);
        }
    } else {
        fold_kernel<<<CIN, 64, 0, stream>>>(W, As_, Ad_, COUT, CP, B.Wf, B.Wft);
        gemm_bn<<<dim3(1, NN / 64), 256, 0, stream>>>(xin, B.Wf, B.scale, B.shift, CIN, 64, B.Sbuf);
        repack_wp<<<(KP * 16 + 255) / 256, 256, 0, stream>>>(W, CIN, CP, COUT, B.Wt);
        agg_proj<CIN, CP, COUT><<<dim3(NSLAB, 2), 256, 0, stream>>>(
            B.xbn, B.Sbuf, B.rowptr, B.colsrc, B.Wt, Bv, xout);
    }
}

extern "C" void kernel_launch(void* const* d_in, const int* in_sizes, int n_in,
                              void* d_out, int out_size, void* d_ws, size_t ws_size,
                              hipStream_t stream) {
    (void)in_sizes; (void)n_in; (void)out_size;
    const float* x     = (const float*)d_in[0];
    const int*   ei    = (const int*)d_in[1];
    const int*   batch = (const int*)d_in[2];
    const float* cond  = (const float*)d_in[3];
    const float* W[4]  = {(const float*)d_in[4],  (const float*)d_in[8],
                          (const float*)d_in[12], (const float*)d_in[16]};
    const float* Asp[4] = {(const float*)d_in[5],  (const float*)d_in[9],
                           (const float*)d_in[13], (const float*)d_in[17]};
    const float* Adp[4] = {(const float*)d_in[6],  (const float*)d_in[10],
                           (const float*)d_in[14], (const float*)d_in[18]};
    const float* Bv[4]  = {(const float*)d_in[7],  (const float*)d_in[11],
                           (const float*)d_in[15], (const float*)d_in[19]};
    const float* G[4]   = {(const float*)d_in[20], (const float*)d_in[22],
                           (const float*)d_in[24], (const float*)d_in[26]};
    const float* Be[4]  = {(const float*)d_in[21], (const float*)d_in[23],
                           (const float*)d_in[25], (const float*)d_in[27]};
    const float* fcW = (const float*)d_in[30];
    const float* fcb = (const float*)d_in[31];
    float* out = (float*)d_out;

    char* base = (char*)d_ws;
    size_t off = 0;
    auto alloc = [&](size_t b) {
        size_t o = off;
        off += (b + 255) & ~(size_t)255;
        return (void*)(base + o);
    };
    unsigned short* zbuf = (unsigned short*)alloc((size_t)NSLAB * 4096 * 2);
    unsigned short* xbn  = (unsigned short*)alloc((size_t)NN * 128 * 2);
    unsigned short* Wt   = (unsigned short*)alloc((size_t)96 * 4096 * 2);
    unsigned short* Wft  = (unsigned short*)alloc((size_t)64 * 128 * 2);
    float* pbuf    = (float*)alloc((size_t)NSLAB * 96 * 4);
    float* xbuf    = (float*)alloc((size_t)NN * 90 * 4);
    float* Sbuf    = (float*)alloc((size_t)NN * 64 * 4);
    float* partial = (float*)alloc((size_t)256 * 2 * 128 * 4);
    float* scale   = (float*)alloc(128 * 4);
    float* shift   = (float*)alloc(128 * 4);
    float* Wf      = (float*)alloc(128 * 64 * 4);
    int* deg     = (int*)alloc((size_t)NN * 4);
    int* rowptr  = (int*)alloc((size_t)(NN + 1) * 4);
    int* cursor  = (int*)alloc((size_t)NN * 4);
    int* colsrc  = (int*)alloc((size_t)(NE + NN) * 4);
    int* bsum    = (int*)alloc((size_t)SCB * 4);
    int* boff    = (int*)alloc((size_t)SCB * 4);
    if (off > ws_size) return;

    const int* srcp = ei;
    const int* dstp = ei + NE;

    // CSR by dst (hierarchical scan)
    deg_init<<<(NN + 255) / 256, 256, 0, stream>>>(deg);
    count_kernel<<<(NE + 255) / 256, 256, 0, stream>>>(dstp, deg);
    scan_pass1<<<SCB, 256, 0, stream>>>(deg, bsum);
    scan_pass2<<<1, 256, 0, stream>>>(bsum, boff, rowptr);
    scan_pass3<<<SCB, 256, 0, stream>>>(deg, boff, rowptr, cursor);
    scatter_edges<<<(NE + 255) / 256, 256, 0, stream>>>(srcp, dstp, cursor, colsrc);
    scatter_self<<<(NN + 255) / 256, 256, 0, stream>>>(cursor, colsrc);

    LayerBufs B{partial, scale, shift, Wf, Wft, xbn, Wt, zbuf, Sbuf, pbuf, rowptr, colsrc};

    // L1: 128 -> 90 ; L2: 90 -> 45 ; L3: 45 -> 15 ; L4: 15 -> 5
    run_layer<128, 128, 90, 96, 6, 4>(x,    W[0], Asp[0], Adp[0], Bv[0], G[0], Be[0], xbuf, B, stream);
    run_layer< 90,  96, 45, 48, 3, 4>(xbuf, W[1], Asp[1], Adp[1], Bv[1], G[1], Be[1], xbuf, B, stream);
    run_layer< 45,  48, 15, 16, 1, 4>(xbuf, W[2], Asp[2], Adp[2], Bv[2], G[2], Be[2], xbuf, B, stream);
    run_layer< 15,  16,  5, 16, 1, 2>(xbuf, W[3], Asp[3], Adp[3], Bv[3], G[3], Be[3], xbuf, B, stream);

    pool_head<<<256, 64, 0, stream>>>(xbuf, batch, cond, fcW, fcb, out);
}

// Round 14
// 1408.403 us; speedup vs baseline: 1.0346x; 1.0346x over previous
//
#include <hip/hip_runtime.h>
#include <hip/hip_bf16.h>

// ---------------- constants ----------------
constexpr int NN = 40000;   // nodes
constexpr int NE = 400000;  // edges (before self-loops)
constexpr int NSLAB = 20000;
constexpr int MPAD = 20096; // 157 * 128 (M-tile overrun padding)
constexpr int SCB = 256;    // scan blocks
constexpr int SCHUNK = (NN + SCB - 1) / SCB;   // 157 (<= 256)

__device__ __forceinline__ unsigned short f2bf(float f) {
    unsigned int u = __float_as_uint(f);
    unsigned int r = (u + 0x7FFFu + ((u >> 16) & 1u)) >> 16;
    return (unsigned short)r;
}

// async global->LDS 16B: no VGPR round-trip, loads issue back-to-back.
__device__ __forceinline__ void load_lds16(const unsigned short* g, unsigned short* l) {
    __builtin_amdgcn_global_load_lds(
        (const __attribute__((address_space(1))) unsigned int*)(g),
        (__attribute__((address_space(3))) unsigned int*)(l), 16, 0, 0);
}

typedef __attribute__((ext_vector_type(8))) short bf16x8;
typedef __attribute__((ext_vector_type(4))) float f32x4;
typedef __attribute__((ext_vector_type(2))) float floatx2;

// ---------------- BN ----------------
__global__ void bn_partial(const float* __restrict__ x, int N, int C,
                           float* __restrict__ partial) {
    int ch = threadIdx.x;            // blockDim = 128, C <= 128
    if (ch >= C) return;
    float s = 0.f, sq = 0.f;
    for (int n = blockIdx.x; n < N; n += gridDim.x) {
        float v = x[(size_t)n * C + ch];
        s += v; sq += v * v;
    }
    partial[(size_t)blockIdx.x * 2 * C + ch]     = s;
    partial[(size_t)blockIdx.x * 2 * C + C + ch] = sq;
}

__global__ void bn_finalize(const float* __restrict__ partial, int nb, int C, float fN,
                            const float* __restrict__ g, const float* __restrict__ be,
                            float* __restrict__ scale, float* __restrict__ shift) {
    int ch = threadIdx.x;
    if (ch >= C) return;
    float s = 0.f, sq = 0.f;
    for (int b = 0; b < nb; ++b) {
        s  += partial[(size_t)b * 2 * C + ch];
        sq += partial[(size_t)b * 2 * C + C + ch];
    }
    float mean = s / fN;
    float var  = sq / fN - mean * mean;
    float inv  = rsqrtf(var + 1e-5f);
    float sc   = g[ch] * inv;
    scale[ch] = sc;
    shift[ch] = be[ch] - mean * sc;
}

// xbn[n, c] (bf16, stride CP, zero-padded c>=CIN) = scale*x+shift
template <int CIN, int CP>
__global__ void bn_apply(const float* __restrict__ x, const float* __restrict__ scale,
                         const float* __restrict__ shift, unsigned short* __restrict__ xbn) {
    int idx = blockIdx.x * blockDim.x + threadIdx.x;
    if (idx >= NN * CP) return;
    int n = idx / CP, c = idx % CP;
    float v = 0.f;
    if (c < CIN) v = scale[c] * x[(size_t)n * CIN + c] + shift[c];
    xbn[idx] = f2bf(v);
}

// ---------------- fold a_src/a_dst into W:  Wf[cin, j]  +  bf16 Wft[j][CP] ----------
__global__ void fold_kernel(const float* __restrict__ W, const float* __restrict__ as_,
                            const float* __restrict__ ad_, int C, int CP,
                            float* __restrict__ Wf, unsigned short* __restrict__ Wft) {
    int cin = blockIdx.x;
    int j = threadIdx.x;             // 64
    int h = j & 31;
    const float* a = (j < 32) ? as_ : ad_;
    const float* wrow = W + (size_t)cin * 32 * C + (size_t)h * C;
    const float* arow = a + (size_t)h * C;
    float s = 0.f;
    for (int c = 0; c < C; ++c) s += wrow[c] * arow[c];
    Wf[cin * 64 + j] = s;
    Wft[j * CP + cin] = f2bf(s);
}

// Wt[c][h*CP + k] = W[k][h*COUT + c] / 32  (bf16, zero-padded), c in [0,NP)
__global__ void repack_w(const float* __restrict__ W, int CIN, int CP, int COUT,
                         unsigned short* __restrict__ Wt) {
    int c = blockIdx.x;              // [0, NP)
    for (int kk = threadIdx.x; kk < 32 * CP; kk += blockDim.x) {
        int h = kk / CP, k = kk % CP;
        float v = 0.f;
        if (c < COUT && k < CIN) v = W[(size_t)k * (32 * COUT) + h * COUT + c] * (1.f / 32.f);
        Wt[(size_t)c * (32 * CP) + kk] = f2bf(v);
    }
}

// ---------------- MFMA score GEMM: Sbuf[n, 0:64] = xbn[n,:] @ Wft^T ------------------
template <int KP>
__global__ __launch_bounds__(256) void gemm_s(const unsigned short* __restrict__ xbn,
                                              const unsigned short* __restrict__ Wft,
                                              float* __restrict__ Sbuf) {
    constexpr int NC = KP / 32;
    __shared__ unsigned short Ab[64 * 32];
    __shared__ unsigned short Bb[64 * 32];
    const int m0 = blockIdx.x * 64;
    const int tid = threadIdx.x;
    const int wv = tid >> 6, lane = tid & 63;
    const int mm = lane & 15, quad = lane >> 4;
    f32x4 acc[4];
#pragma unroll
    for (int t = 0; t < 4; ++t) acc[t] = f32x4{0.f, 0.f, 0.f, 0.f};

    for (int c = 0; c < NC; ++c) {
        int row = tid >> 2, gc = tid & 3;
        load_lds16(xbn + (size_t)(m0 + row) * KP + c * 32 + gc * 8, Ab + (size_t)tid * 8);
        load_lds16(Wft + (size_t)row * KP + c * 32 + gc * 8, Bb + (size_t)tid * 8);
        asm volatile("s_waitcnt vmcnt(0)" ::: "memory");
        __syncthreads();
        bf16x8 a = *reinterpret_cast<const bf16x8*>(&Ab[(wv * 16 + mm) * 32 + quad * 8]);
#pragma unroll
        for (int t = 0; t < 4; ++t) {
            bf16x8 b = *reinterpret_cast<const bf16x8*>(&Bb[(t * 16 + mm) * 32 + quad * 8]);
            acc[t] = __builtin_amdgcn_mfma_f32_16x16x32_bf16(a, b, acc[t], 0, 0, 0);
        }
        __syncthreads();
    }
    int rbase = m0 + wv * 16 + quad * 4;
#pragma unroll
    for (int t = 0; t < 4; ++t)
#pragma unroll
        for (int r = 0; r < 4; ++r)
            Sbuf[(size_t)(rbase + r) * 64 + t * 16 + mm] = acc[t][r];
}

// ---------------- fp32 GEMM with fused BN on A (score GEMM for small-K layers) ----
__global__ __launch_bounds__(256) void gemm_bn(const float* __restrict__ X,
                                               const float* __restrict__ W,
                                               const float* __restrict__ scale,
                                               const float* __restrict__ shift,
                                               int Cin, int HC, float* __restrict__ OUT) {
    __shared__ float As[8][64];
    __shared__ float Bs[8][64];
    int tid = threadIdx.x;
    int n0 = blockIdx.y * 64;
    int j0 = blockIdx.x * 64;
    int tr = tid >> 4, tc = tid & 15;
    float acc[4][4] = {};
    for (int k0 = 0; k0 < Cin; k0 += 8) {
        int idx = tid;
#pragma unroll
        for (int it = 0; it < 2; ++it, idx += 256) {
            int row = idx >> 3, kk = idx & 7;
            int k = k0 + kk;
            float v = 0.f;
            if (k < Cin) v = scale[k] * X[(size_t)(n0 + row) * Cin + k] + shift[k];
            As[kk][row] = v;
        }
        int idx2 = tid;
#pragma unroll
        for (int it = 0; it < 2; ++it, idx2 += 256) {
            int col = idx2 & 63, kr = idx2 >> 6;
            int k = k0 + kr, j = j0 + col;
            float v = 0.f;
            if (k < Cin && j < HC) v = W[(size_t)k * HC + j];
            Bs[kr][col] = v;
        }
        __syncthreads();
#pragma unroll
        for (int kk = 0; kk < 8; ++kk) {
            float a[4], b[4];
#pragma unroll
            for (int i = 0; i < 4; ++i) a[i] = As[kk][tr * 4 + i];
#pragma unroll
            for (int j = 0; j < 4; ++j) b[j] = Bs[kk][tc * 4 + j];
#pragma unroll
            for (int i = 0; i < 4; ++i)
#pragma unroll
                for (int j = 0; j < 4; ++j) acc[i][j] += a[i] * b[j];
        }
        __syncthreads();
    }
#pragma unroll
    for (int i = 0; i < 4; ++i) {
        int row = n0 + tr * 4 + i;
#pragma unroll
        for (int j = 0; j < 4; ++j) {
            int col = j0 + tc * 4 + j;
            if (col < HC) OUT[(size_t)row * HC + col] = acc[i][j];
        }
    }
}

// ---------------- CSR build (hierarchical 3-pass scan) ----------------
__global__ void deg_init(int* __restrict__ deg) {
    int n = blockIdx.x * blockDim.x + threadIdx.x;
    if (n < NN) deg[n] = 1;   // self-loop
}
__global__ void count_kernel(const int* __restrict__ dst, int* __restrict__ deg) {
    int e = blockIdx.x * blockDim.x + threadIdx.x;
    if (e < NE) atomicAdd(&deg[dst[e]], 1);
}
__global__ void scan_pass1(const int* __restrict__ deg, int* __restrict__ bsum) {
    __shared__ int red[256];
    int b = blockIdx.x, t = threadIdx.x;
    int lo = b * SCHUNK, hi = min(lo + SCHUNK, NN);
    int s = 0;
    for (int i = lo + t; i < hi; i += 256) s += deg[i];
    red[t] = s;
    __syncthreads();
    for (int off = 128; off > 0; off >>= 1) {
        if (t < off) red[t] += red[t + off];
        __syncthreads();
    }
    if (t == 0) bsum[b] = red[0];
}
__global__ void scan_pass2(const int* __restrict__ bsum, int* __restrict__ boff,
                           int* __restrict__ rowptr) {
    __shared__ int lds[256];
    int t = threadIdx.x;
    int v0 = bsum[t];
    lds[t] = v0;
    __syncthreads();
    for (int off = 1; off < 256; off <<= 1) {
        int v = (t >= off) ? lds[t - off] : 0;
        __syncthreads();
        lds[t] += v;
        __syncthreads();
    }
    boff[t] = lds[t] - v0;          // exclusive
    if (t == 255) rowptr[NN] = lds[255];
}
__global__ void scan_pass3(const int* __restrict__ deg, const int* __restrict__ boff,
                           int* __restrict__ rowptr, int* __restrict__ cursor) {
    __shared__ int lds[256];
    int b = blockIdx.x, t = threadIdx.x;
    int i = b * SCHUNK + t;
    int d = (t < SCHUNK && i < NN) ? deg[i] : 0;
    lds[t] = d;
    __syncthreads();
    for (int off = 1; off < 256; off <<= 1) {
        int v = (t >= off) ? lds[t - off] : 0;
        __syncthreads();
        lds[t] += v;
        __syncthreads();
    }
    if (t < SCHUNK && i < NN) {
        int excl = lds[t] - d + boff[b];
        rowptr[i] = excl;
        cursor[i] = excl;
    }
}
__global__ void scatter_edges(const int* __restrict__ src, const int* __restrict__ dst,
                              int* __restrict__ cursor, int* __restrict__ colsrc) {
    int e = blockIdx.x * blockDim.x + threadIdx.x;
    if (e < NE) {
        int pos = atomicAdd(&cursor[dst[e]], 1);
        colsrc[pos] = src[e];
    }
}
__global__ void scatter_self(int* __restrict__ cursor, int* __restrict__ colsrc) {
    int n = blockIdx.x * blockDim.x + threadIdx.x;
    if (n < NN) {
        int pos = atomicAdd(&cursor[n], 1);
        colsrc[pos] = n;
    }
}

// ---------------- pass A: softmax-aggregate xbn -> z[n, 32*CP] (bf16) ----------------
template <int CIN, int CP>
__global__ __launch_bounds__(256) void agg_x(const unsigned short* __restrict__ xbn,
                                             const float* __restrict__ S,
                                             const int* __restrict__ rowptr,
                                             const int* __restrict__ colsrc,
                                             int n0, unsigned short* __restrict__ z) {
    constexpr int BS = 256, CH = 32, J = CP / 8;   // J = 16,12,6,2
    constexpr bool V4 = (J % 4 == 0);
    constexpr int NACC = V4 ? (J / 4) : (J / 2);
    __shared__ float x_lds[CH * CP];
    __shared__ float w_lds[CH * 32];
    __shared__ int cs_lds[CH];
    __shared__ float sdst[32], m_lds[32], d_lds[32], r_lds[32];
    __shared__ float red[8][32];

    int n = n0 + blockIdx.x;
    int tid = threadIdx.x;
    int start = rowptr[n], end = rowptr[n + 1];
    if (tid < 32) {
        sdst[tid] = S[(size_t)n * 64 + 32 + tid];
        m_lds[tid] = -INFINITY;
        d_lds[tid] = 0.f;
    }
    const int h = tid & 31, g = tid >> 5;
    const int cbase = g * J;
    f32x4 acc4[V4 ? NACC : 1];
    floatx2 acc2[V4 ? 1 : NACC];
    if constexpr (V4) {
#pragma unroll
        for (int j = 0; j < NACC; ++j) acc4[j] = f32x4{0.f, 0.f, 0.f, 0.f};
    } else {
#pragma unroll
        for (int j = 0; j < NACC; ++j) acc2[j] = floatx2{0.f, 0.f};
    }

    for (int chunk = start; chunk < end; chunk += CH) {
        int ce = min(CH, end - chunk);
        int ce32 = ce * 32;
        if (tid < 32 && tid < ce) cs_lds[tid] = colsrc[chunk + tid];
        __syncthreads();

        float lreg[4];
        float pmx = -INFINITY;
#pragma unroll
        for (int p = 0; p < 4; ++p) {
            int idx = p * 256 + tid;
            lreg[p] = -INFINITY;
            if (idx < ce32) {
                int e = idx >> 5;
                float l = S[(size_t)cs_lds[e] * 64 + h] + sdst[h];
                l = l > 0.f ? l : 0.2f * l;
                lreg[p] = l;
                pmx = fmaxf(pmx, l);
            }
        }
        red[g][h] = pmx;
        for (int idx = tid; idx < ce * (CP / 2); idx += BS) {
            int e = idx / (CP / 2), c2 = idx % (CP / 2);
            unsigned int u =
                reinterpret_cast<const unsigned int*>(xbn)[(size_t)cs_lds[e] * (CP / 2) + c2];
            x_lds[e * CP + 2 * c2]     = __uint_as_float(u << 16);
            x_lds[e * CP + 2 * c2 + 1] = __uint_as_float(u & 0xFFFF0000u);
        }
        __syncthreads();
        if (tid < 32) {
            float cm = red[0][tid];
#pragma unroll
            for (int s2 = 1; s2 < 8; ++s2) cm = fmaxf(cm, red[s2][tid]);
            float oldm = m_lds[tid], newm = fmaxf(oldm, cm);
            r_lds[tid] = (oldm == -INFINITY) ? 0.f : __expf(oldm - newm);
            m_lds[tid] = newm;
        }
        __syncthreads();
        {
            float mh = m_lds[h];
            float ps = 0.f;
#pragma unroll
            for (int p = 0; p < 4; ++p) {
                int idx = p * 256 + tid;
                if (idx < ce32) {
                    float v = __expf(lreg[p] - mh);
                    w_lds[idx] = v;
                    ps += v;
                }
            }
            red[g][h] = ps;
        }
        __syncthreads();
        if (tid < 32) {
            float ss = 0.f;
#pragma unroll
            for (int s2 = 0; s2 < 8; ++s2) ss += red[s2][tid];
            d_lds[tid] = d_lds[tid] * r_lds[tid] + ss;
        }
        float rr = r_lds[h];
        if constexpr (V4) {
            f32x4 rr4 = {rr, rr, rr, rr};
#pragma unroll
            for (int j = 0; j < NACC; ++j) acc4[j] *= rr4;
            for (int e = 0; e < ce; ++e) {
                float w = w_lds[e * 32 + h];
                f32x4 w4 = {w, w, w, w};
                const f32x4* xv = reinterpret_cast<const f32x4*>(&x_lds[e * CP + cbase]);
#pragma unroll
                for (int j = 0; j < NACC; ++j) acc4[j] += w4 * xv[j];
            }
        } else {
            floatx2 rr2 = {rr, rr};
#pragma unroll
            for (int j = 0; j < NACC; ++j) acc2[j] *= rr2;
            for (int e = 0; e < ce; ++e) {
                float w = w_lds[e * 32 + h];
                floatx2 w2 = {w, w};
                const floatx2* xv = reinterpret_cast<const floatx2*>(&x_lds[e * CP + cbase]);
#pragma unroll
                for (int j = 0; j < NACC; ++j) acc2[j] += w2 * xv[j];
            }
        }
    }
    __syncthreads();
    float dinv = 1.f / d_lds[h];
    unsigned int* zp = reinterpret_cast<unsigned int*>(
        z + (size_t)(n - n0) * (32 * CP) + h * CP + cbase);
    if constexpr (V4) {
#pragma unroll
        for (int j = 0; j < NACC; ++j) {
            zp[2 * j]     = (unsigned int)f2bf(acc4[j][0] * dinv)
                          | ((unsigned int)f2bf(acc4[j][1] * dinv) << 16);
            zp[2 * j + 1] = (unsigned int)f2bf(acc4[j][2] * dinv)
                          | ((unsigned int)f2bf(acc4[j][3] * dinv) << 16);
        }
    } else {
#pragma unroll
        for (int j = 0; j < NACC; ++j) {
            zp[j] = (unsigned int)f2bf(acc2[j][0] * dinv)
                  | ((unsigned int)f2bf(acc2[j][1] * dinv) << 16);
        }
    }
}

// ---------------- pass B: LDS-tiled MFMA GEMM, atomic K-split ----------------
// Round-13: atomic accumulation (4 spread writers/address) replaced 4-part pbuf
// materialization — kept (saved ~160 us). Round-13's agg_proj fusion for L3/L4
// REVERTED: its 90 uncoalesced scalar global loads/thread cost 374 us vs ~130 us
// for this separate path (HBM was only 3.7% — fusing saved bytes it didn't need).
template <int NT, int KP, int KS>
__global__ __launch_bounds__(256) void gemm_z_t(const unsigned short* __restrict__ z,
                                                const unsigned short* __restrict__ Wt,
                                                float* __restrict__ obuf) {
    constexpr int NP = NT * 16;
    constexpr int KSEG = KP / KS;       // multiple of 64
    constexpr int NC = KSEG / 64;
    constexpr int MT = 128;
    __shared__ unsigned short Abuf[2][MT * 64];
    __shared__ unsigned short Bbuf[2][NP * 64];

    const int m0 = blockIdx.x * MT;
    const int kbeg = blockIdx.y * KSEG;
    const int tid = threadIdx.x;
    const int wv = tid >> 6;
    const int lane = tid & 63;
    const int mm = lane & 15, quad = lane >> 4;

    auto stage = [&](int buf, int kk) {
#pragma unroll
        for (int it = 0; it < 4; ++it) {
            int gi = it * 256 + tid;
            int row = gi >> 3, gc = gi & 7;
            int srow = m0 + row;
            if (srow > NSLAB - 1) srow = NSLAB - 1;
            const unsigned short* src = z + (size_t)srow * KP + kk + gc * 8;
            unsigned short* dst = &Abuf[buf][(size_t)(it * 256 + wv * 64) * 8];
            load_lds16(src, dst);
        }
#pragma unroll
        for (int it = 0; it < (NP * 8 + 255) / 256; ++it) {
            int gi = it * 256 + tid;
            if (gi < NP * 8) {
                int row = gi >> 3, gc = gi & 7;
                const unsigned short* src = Wt + (size_t)row * KP + kk + gc * 8;
                unsigned short* dst = &Bbuf[buf][(size_t)(it * 256 + wv * 64) * 8];
                load_lds16(src, dst);
            }
        }
    };

    f32x4 acc[2][NT];
#pragma unroll
    for (int f = 0; f < 2; ++f)
#pragma unroll
        for (int t = 0; t < NT; ++t) acc[f][t] = f32x4{0.f, 0.f, 0.f, 0.f};

    stage(0, kbeg);
    for (int c = 0; c < NC; ++c) {
        asm volatile("s_waitcnt vmcnt(0)" ::: "memory");
        __syncthreads();
        int cur = c & 1;
        if (c + 1 < NC) stage(cur ^ 1, kbeg + (c + 1) * 64);
        const unsigned short* Ab = Abuf[cur];
        const unsigned short* Bb = Bbuf[cur];
#pragma unroll
        for (int hh = 0; hh < 2; ++hh) {
            bf16x8 a0 = *reinterpret_cast<const bf16x8*>(&Ab[(wv * 32 + mm) * 64 + hh * 32 + quad * 8]);
            bf16x8 a1 = *reinterpret_cast<const bf16x8*>(&Ab[(wv * 32 + 16 + mm) * 64 + hh * 32 + quad * 8]);
#pragma unroll
            for (int t = 0; t < NT; ++t) {
                bf16x8 b = *reinterpret_cast<const bf16x8*>(&Bb[(t * 16 + mm) * 64 + hh * 32 + quad * 8]);
                acc[0][t] = __builtin_amdgcn_mfma_f32_16x16x32_bf16(a0, b, acc[0][t], 0, 0, 0);
                acc[1][t] = __builtin_amdgcn_mfma_f32_16x16x32_bf16(a1, b, acc[1][t], 0, 0, 0);
            }
        }
        __syncthreads();
    }

    int row0 = quad * 4;
#pragma unroll
    for (int f = 0; f < 2; ++f) {
#pragma unroll
        for (int t = 0; t < NT; ++t) {
            int cc = t * 16 + mm;
#pragma unroll
            for (int r = 0; r < 4; ++r) {
                int m = m0 + wv * 32 + f * 16 + row0 + r;
                if (m < NSLAB) atomicAdd(&obuf[(size_t)m * NP + cc], acc[f][t][r]);
            }
        }
    }
}

// bias + leaky 0.01 -> xout
__global__ void bias_leaky(const float* __restrict__ obuf, int NPAD, int COUT,
                           const float* __restrict__ bias, int n0,
                           float* __restrict__ xout) {
    int idx = blockIdx.x * blockDim.x + threadIdx.x;
    if (idx >= NSLAB * NPAD) return;
    int m = idx / NPAD, c = idx % NPAD;
    if (c >= COUT) return;
    float v = obuf[idx] + bias[c];
    v = v > 0.f ? v : 0.01f * v;
    xout[(size_t)(n0 + m) * COUT + c] = v;
}

// ---------------- fused mean-pool + FC + sigmoid ----------------
__global__ __launch_bounds__(64) void pool_head(const float* __restrict__ x4,
                                                const int* __restrict__ batch,
                                                const float* __restrict__ cond,
                                                const float* __restrict__ fcW,
                                                const float* __restrict__ fcb,
                                                float* __restrict__ out) {
    int g = blockIdx.x;
    int lane = threadIdx.x;
    int lo = 0, hi = NN;
    while (lo < hi) { int mid = (lo + hi) >> 1; if (batch[mid] < g) lo = mid + 1; else hi = mid; }
    int lo2 = lo, hi2 = NN;
    while (lo2 < hi2) { int mid = (lo2 + hi2) >> 1; if (batch[mid] < g + 1) lo2 = mid + 1; else hi2 = mid; }
    int beg = lo, end = lo2;

    float s[5] = {0.f, 0.f, 0.f, 0.f, 0.f};
    for (int n = beg + lane; n < end; n += 64) {
#pragma unroll
        for (int c = 0; c < 5; ++c) s[c] += x4[(size_t)n * 5 + c];
    }
    float cz = 0.f;
    if (lane < 100) cz = cond[lane] * fcW[5 + lane];
    if (lane + 64 < 100) cz += cond[lane + 64] * fcW[5 + lane + 64];
#pragma unroll
    for (int off = 32; off > 0; off >>= 1) {
#pragma unroll
        for (int c = 0; c < 5; ++c) s[c] += __shfl_down(s[c], off, 64);
        cz += __shfl_down(cz, off, 64);
    }
    if (lane == 0) {
        float cnt = fmaxf((float)(end - beg), 1.f);
        float zv = fcb[0] + cz;
#pragma unroll
        for (int c = 0; c < 5; ++c) zv += (s[c] / cnt) * fcW[c];
        out[g] = 1.f / (1.f + __expf(-zv));
    }
}

// ---------------- per-layer driver ----------------
struct LayerBufs {
    float* partial; float* scale; float* shift; float* Wf;
    unsigned short* Wft;
    unsigned short* xbn; unsigned short* Wt; unsigned short* zbuf;
    float* Sbuf; float* pbuf; const int* rowptr; const int* colsrc;
};

template <int CIN, int CP, int COUT, int NP, int NT, int KS>
static void run_layer(const float* xin, const float* W, const float* As_, const float* Ad_,
                      const float* Bv, const float* G, const float* Be,
                      float* xout, const LayerBufs& B, hipStream_t stream) {
    constexpr int KP = 32 * CP;
    constexpr int NPAD = NT * 16;
    bn_partial<<<256, 128, 0, stream>>>(xin, NN, CIN, B.partial);
    bn_finalize<<<1, 128, 0, stream>>>(B.partial, 256, CIN, (float)NN, G, Be, B.scale, B.shift);
    bn_apply<CIN, CP><<<(NN * CP + 255) / 256, 256, 0, stream>>>(xin, B.scale, B.shift, B.xbn);
    if constexpr (CP >= 64) {
        hipMemsetAsync(B.Wft, 0, (size_t)64 * CP * 2, stream);
        fold_kernel<<<CIN, 64, 0, stream>>>(W, As_, Ad_, COUT, CP, B.Wf, B.Wft);
        gemm_s<CP><<<NN / 64, 256, 0, stream>>>(B.xbn, B.Wft, B.Sbuf);
    } else {
        fold_kernel<<<CIN, 64, 0, stream>>>(W, As_, Ad_, COUT, CP, B.Wf, B.Wft);
        gemm_bn<<<dim3(1, NN / 64), 256, 0, stream>>>(xin, B.Wf, B.scale, B.shift, CIN, 64, B.Sbuf);
    }
    repack_w<<<NP, 256, 0, stream>>>(W, CIN, CP, COUT, B.Wt);
    for (int s = 0; s < 2; ++s) {
        int n0 = s * NSLAB;
        hipMemsetAsync(B.pbuf, 0, (size_t)NSLAB * NPAD * 4, stream);
        agg_x<CIN, CP><<<NSLAB, 256, 0, stream>>>(B.xbn, B.Sbuf, B.rowptr, B.colsrc, n0, B.zbuf);
        gemm_z_t<NT, KP, KS><<<dim3(MPAD / 128, KS), 256, 0, stream>>>(B.zbuf, B.Wt, B.pbuf);
        bias_leaky<<<(NSLAB * NPAD + 255) / 256, 256, 0, stream>>>(
            B.pbuf, NPAD, COUT, Bv, n0, xout);
    }
}

extern "C" void kernel_launch(void* const* d_in, const int* in_sizes, int n_in,
                              void* d_out, int out_size, void* d_ws, size_t ws_size,
                              hipStream_t stream) {
    (void)in_sizes; (void)n_in; (void)out_size;
    const float* x     = (const float*)d_in[0];
    const int*   ei    = (const int*)d_in[1];
    const int*   batch = (const int*)d_in[2];
    const float* cond  = (const float*)d_in[3];
    const float* W[4]  = {(const float*)d_in[4],  (const float*)d_in[8],
                          (const float*)d_in[12], (const float*)d_in[16]};
    const float* Asp[4] = {(const float*)d_in[5],  (const float*)d_in[9],
                           (const float*)d_in[13], (const float*)d_in[17]};
    const float* Adp[4] = {(const float*)d_in[6],  (const float*)d_in[10],
                           (const float*)d_in[14], (const float*)d_in[18]};
    const float* Bv[4]  = {(const float*)d_in[7],  (const float*)d_in[11],
                           (const float*)d_in[15], (const float*)d_in[19]};
    const float* G[4]   = {(const float*)d_in[20], (const float*)d_in[22],
                           (const float*)d_in[24], (const float*)d_in[26]};
    const float* Be[4]  = {(const float*)d_in[21], (const float*)d_in[23],
                           (const float*)d_in[25], (const float*)d_in[27]};
    const float* fcW = (const float*)d_in[30];
    const float* fcb = (const float*)d_in[31];
    float* out = (float*)d_out;

    char* base = (char*)d_ws;
    size_t off = 0;
    auto alloc = [&](size_t b) {
        size_t o = off;
        off += (b + 255) & ~(size_t)255;
        return (void*)(base + o);
    };
    unsigned short* zbuf = (unsigned short*)alloc((size_t)NSLAB * 4096 * 2);
    unsigned short* xbn  = (unsigned short*)alloc((size_t)NN * 128 * 2);
    unsigned short* Wt   = (unsigned short*)alloc((size_t)96 * 4096 * 2);
    unsigned short* Wft  = (unsigned short*)alloc((size_t)64 * 128 * 2);
    float* pbuf    = (float*)alloc((size_t)NSLAB * 96 * 4);
    float* xbuf    = (float*)alloc((size_t)NN * 90 * 4);
    float* Sbuf    = (float*)alloc((size_t)NN * 64 * 4);
    float* partial = (float*)alloc((size_t)256 * 2 * 128 * 4);
    float* scale   = (float*)alloc(128 * 4);
    float* shift   = (float*)alloc(128 * 4);
    float* Wf      = (float*)alloc(128 * 64 * 4);
    int* deg     = (int*)alloc((size_t)NN * 4);
    int* rowptr  = (int*)alloc((size_t)(NN + 1) * 4);
    int* cursor  = (int*)alloc((size_t)NN * 4);
    int* colsrc  = (int*)alloc((size_t)(NE + NN) * 4);
    int* bsum    = (int*)alloc((size_t)SCB * 4);
    int* boff    = (int*)alloc((size_t)SCB * 4);
    if (off > ws_size) return;

    const int* srcp = ei;
    const int* dstp = ei + NE;

    // CSR by dst (hierarchical scan)
    deg_init<<<(NN + 255) / 256, 256, 0, stream>>>(deg);
    count_kernel<<<(NE + 255) / 256, 256, 0, stream>>>(dstp, deg);
    scan_pass1<<<SCB, 256, 0, stream>>>(deg, bsum);
    scan_pass2<<<1, 256, 0, stream>>>(bsum, boff, rowptr);
    scan_pass3<<<SCB, 256, 0, stream>>>(deg, boff, rowptr, cursor);
    scatter_edges<<<(NE + 255) / 256, 256, 0, stream>>>(srcp, dstp, cursor, colsrc);
    scatter_self<<<(NN + 255) / 256, 256, 0, stream>>>(cursor, colsrc);

    LayerBufs B{partial, scale, shift, Wf, Wft, xbn, Wt, zbuf, Sbuf, pbuf, rowptr, colsrc};

    // L1: 128 -> 90 ; L2: 90 -> 45 ; L3: 45 -> 15 ; L4: 15 -> 5
    run_layer<128, 128, 90, 96, 6, 4>(x,    W[0], Asp[0], Adp[0], Bv[0], G[0], Be[0], xbuf, B, stream);
    run_layer< 90,  96, 45, 48, 3, 4>(xbuf, W[1], Asp[1], Adp[1], Bv[1], G[1], Be[1], xbuf, B, stream);
    run_layer< 45,  48, 15, 16, 1, 4>(xbuf, W[2], Asp[2], Adp[2], Bv[2], G[2], Be[2], xbuf, B, stream);
    run_layer< 15,  16,  5, 16, 1, 2>(xbuf, W[3], Asp[3], Adp[3], Bv[3], G[3], Be[3], xbuf, B, stream);

    pool_head<<<256, 64, 0, stream>>>(xbuf, batch, cond, fcW, fcb, out);
}

// Round 16
// 1344.267 us; speedup vs baseline: 1.0839x; 1.0477x over previous
//
#include <hip/hip_runtime.h>
#include <hip/hip_bf16.h>

// ---------------- constants ----------------
constexpr int NN = 40000;   // nodes
constexpr int NE = 400000;  // edges (before self-loops)
constexpr int NSLAB = 20000;
constexpr int MPAD = 20096; // 157 * 128 (M-tile overrun padding)
constexpr int SCB = 256;    // scan blocks
constexpr int SCHUNK = (NN + SCB - 1) / SCB;   // 157 (<= 256)

__device__ __forceinline__ unsigned short f2bf(float f) {
    unsigned int u = __float_as_uint(f);
    unsigned int r = (u + 0x7FFFu + ((u >> 16) & 1u)) >> 16;
    return (unsigned short)r;
}

// async global->LDS 16B: no VGPR round-trip, loads issue back-to-back.
__device__ __forceinline__ void load_lds16(const unsigned short* g, unsigned short* l) {
    __builtin_amdgcn_global_load_lds(
        (const __attribute__((address_space(1))) unsigned int*)(g),
        (__attribute__((address_space(3))) unsigned int*)(l), 16, 0, 0);
}

typedef __attribute__((ext_vector_type(8))) short bf16x8;
typedef __attribute__((ext_vector_type(4))) float f32x4;
typedef __attribute__((ext_vector_type(2))) float floatx2;

// ---------------- BN ----------------
__global__ void bn_partial(const float* __restrict__ x, int N, int C,
                           float* __restrict__ partial) {
    int ch = threadIdx.x;            // blockDim = 128, C <= 128
    if (ch >= C) return;
    float s = 0.f, sq = 0.f;
    for (int n = blockIdx.x; n < N; n += gridDim.x) {
        float v = x[(size_t)n * C + ch];
        s += v; sq += v * v;
    }
    partial[(size_t)blockIdx.x * 2 * C + ch]     = s;
    partial[(size_t)blockIdx.x * 2 * C + C + ch] = sq;
}

__global__ void bn_finalize(const float* __restrict__ partial, int nb, int C, float fN,
                            const float* __restrict__ g, const float* __restrict__ be,
                            float* __restrict__ scale, float* __restrict__ shift) {
    int ch = threadIdx.x;
    if (ch >= C) return;
    float s = 0.f, sq = 0.f;
    for (int b = 0; b < nb; ++b) {
        s  += partial[(size_t)b * 2 * C + ch];
        sq += partial[(size_t)b * 2 * C + C + ch];
    }
    float mean = s / fN;
    float var  = sq / fN - mean * mean;
    float inv  = rsqrtf(var + 1e-5f);
    float sc   = g[ch] * inv;
    scale[ch] = sc;
    shift[ch] = be[ch] - mean * sc;
}

// xbn[n, c] (bf16, stride CP, zero-padded c>=CIN) = scale*x+shift
template <int CIN, int CP>
__global__ void bn_apply(const float* __restrict__ x, const float* __restrict__ scale,
                         const float* __restrict__ shift, unsigned short* __restrict__ xbn) {
    int idx = blockIdx.x * blockDim.x + threadIdx.x;
    if (idx >= NN * CP) return;
    int n = idx / CP, c = idx % CP;
    float v = 0.f;
    if (c < CIN) v = scale[c] * x[(size_t)n * CIN + c] + shift[c];
    xbn[idx] = f2bf(v);
}

// ---------------- fused weight prep: fold (Wf + Wft, zero-padded) + repack (Wt) ----
// blocks [0, CP): fold for cin = bid (zeros when cin >= CIN)
// blocks [CP, CP+NP): repack for c = bid - CP (zeros when c >= COUT or k >= CIN)
__global__ void prep_weights(const float* __restrict__ W, const float* __restrict__ as_,
                             const float* __restrict__ ad_, int CIN, int CP, int COUT,
                             float* __restrict__ Wf, unsigned short* __restrict__ Wft,
                             unsigned short* __restrict__ Wt) {
    int bid = blockIdx.x;
    int tid = threadIdx.x;
    if (bid < CP) {
        int cin = bid;
        if (tid < 64) {
            int j = tid, h = j & 31;
            float s = 0.f;
            if (cin < CIN) {
                const float* a = (j < 32) ? as_ : ad_;
                const float* wrow = W + (size_t)cin * 32 * COUT + (size_t)h * COUT;
                const float* arow = a + (size_t)h * COUT;
                for (int c = 0; c < COUT; ++c) s += wrow[c] * arow[c];
            }
            Wf[cin * 64 + j] = s;
            Wft[j * CP + cin] = f2bf(s);
        }
    } else {
        int c = bid - CP;   // [0, NP)
        for (int kk = tid; kk < 32 * CP; kk += blockDim.x) {
            int h = kk / CP, k = kk % CP;
            float v = 0.f;
            if (k < CIN && c < COUT)   // r15 crash-fix companion: guard c<COUT (OOB read)
                v = W[(size_t)k * (32 * COUT) + h * COUT + c] * (1.f / 32.f);
            Wt[(size_t)c * (32 * CP) + kk] = f2bf(v);
        }
    }
}

// ---------------- MFMA score GEMM: Sbuf[n, 0:64] = xbn[n,:] @ Wft^T ------------------
// CPK is the ROW STRIDE of xbn/Wft = CP (NOT 32*CP!). r15 crash root-cause: this was
// instantiated with KP=32*CP -> ~655 MB OOB reads -> HSA abort.
template <int CPK>
__global__ __launch_bounds__(256) void gemm_s(const unsigned short* __restrict__ xbn,
                                              const unsigned short* __restrict__ Wft,
                                              float* __restrict__ Sbuf) {
    constexpr int NC = CPK / 32;
    __shared__ unsigned short Ab[64 * 32];
    __shared__ unsigned short Bb[64 * 32];
    const int m0 = blockIdx.x * 64;
    const int tid = threadIdx.x;
    const int wv = tid >> 6, lane = tid & 63;
    const int mm = lane & 15, quad = lane >> 4;
    f32x4 acc[4];
#pragma unroll
    for (int t = 0; t < 4; ++t) acc[t] = f32x4{0.f, 0.f, 0.f, 0.f};

    for (int c = 0; c < NC; ++c) {
        int row = tid >> 2, gc = tid & 3;
        load_lds16(xbn + (size_t)(m0 + row) * CPK + c * 32 + gc * 8, Ab + (size_t)tid * 8);
        load_lds16(Wft + (size_t)row * CPK + c * 32 + gc * 8, Bb + (size_t)tid * 8);
        asm volatile("s_waitcnt vmcnt(0)" ::: "memory");
        __syncthreads();
        bf16x8 a = *reinterpret_cast<const bf16x8*>(&Ab[(wv * 16 + mm) * 32 + quad * 8]);
#pragma unroll
        for (int t = 0; t < 4; ++t) {
            bf16x8 b = *reinterpret_cast<const bf16x8*>(&Bb[(t * 16 + mm) * 32 + quad * 8]);
            acc[t] = __builtin_amdgcn_mfma_f32_16x16x32_bf16(a, b, acc[t], 0, 0, 0);
        }
        __syncthreads();
    }
    int rbase = m0 + wv * 16 + quad * 4;
#pragma unroll
    for (int t = 0; t < 4; ++t)
#pragma unroll
        for (int r = 0; r < 4; ++r)
            Sbuf[(size_t)(rbase + r) * 64 + t * 16 + mm] = acc[t][r];
}

// ---------------- fp32 GEMM with fused BN on A (score GEMM for small-K layers) ----
__global__ __launch_bounds__(256) void gemm_bn(const float* __restrict__ X,
                                               const float* __restrict__ W,
                                               const float* __restrict__ scale,
                                               const float* __restrict__ shift,
                                               int Cin, int HC, float* __restrict__ OUT) {
    __shared__ float As[8][64];
    __shared__ float Bs[8][64];
    int tid = threadIdx.x;
    int n0 = blockIdx.y * 64;
    int j0 = blockIdx.x * 64;
    int tr = tid >> 4, tc = tid & 15;
    float acc[4][4] = {};
    for (int k0 = 0; k0 < Cin; k0 += 8) {
        int idx = tid;
#pragma unroll
        for (int it = 0; it < 2; ++it, idx += 256) {
            int row = idx >> 3, kk = idx & 7;
            int k = k0 + kk;
            float v = 0.f;
            if (k < Cin) v = scale[k] * X[(size_t)(n0 + row) * Cin + k] + shift[k];
            As[kk][row] = v;
        }
        int idx2 = tid;
#pragma unroll
        for (int it = 0; it < 2; ++it, idx2 += 256) {
            int col = idx2 & 63, kr = idx2 >> 6;
            int k = k0 + kr, j = j0 + col;
            float v = 0.f;
            if (k < Cin && j < HC) v = W[(size_t)k * HC + j];
            Bs[kr][col] = v;
        }
        __syncthreads();
#pragma unroll
        for (int kk = 0; kk < 8; ++kk) {
            float a[4], b[4];
#pragma unroll
            for (int i = 0; i < 4; ++i) a[i] = As[kk][tr * 4 + i];
#pragma unroll
            for (int j = 0; j < 4; ++j) b[j] = Bs[kk][tc * 4 + j];
#pragma unroll
            for (int i = 0; i < 4; ++i)
#pragma unroll
                for (int j = 0; j < 4; ++j) acc[i][j] += a[i] * b[j];
        }
        __syncthreads();
    }
#pragma unroll
    for (int i = 0; i < 4; ++i) {
        int row = n0 + tr * 4 + i;
#pragma unroll
        for (int j = 0; j < 4; ++j) {
            int col = j0 + tc * 4 + j;
            if (col < HC) OUT[(size_t)row * HC + col] = acc[i][j];
        }
    }
}

// ---------------- CSR build (hierarchical 3-pass scan) ----------------
__global__ void deg_init(int* __restrict__ deg) {
    int n = blockIdx.x * blockDim.x + threadIdx.x;
    if (n < NN) deg[n] = 1;   // self-loop
}
__global__ void count_kernel(const int* __restrict__ dst, int* __restrict__ deg) {
    int e = blockIdx.x * blockDim.x + threadIdx.x;
    if (e < NE) atomicAdd(&deg[dst[e]], 1);
}
__global__ void scan_pass1(const int* __restrict__ deg, int* __restrict__ bsum) {
    __shared__ int red[256];
    int b = blockIdx.x, t = threadIdx.x;
    int lo = b * SCHUNK, hi = min(lo + SCHUNK, NN);
    int s = 0;
    for (int i = lo + t; i < hi; i += 256) s += deg[i];
    red[t] = s;
    __syncthreads();
    for (int off = 128; off > 0; off >>= 1) {
        if (t < off) red[t] += red[t + off];
        __syncthreads();
    }
    if (t == 0) bsum[b] = red[0];
}
__global__ void scan_pass2(const int* __restrict__ bsum, int* __restrict__ boff,
                           int* __restrict__ rowptr) {
    __shared__ int lds[256];
    int t = threadIdx.x;
    int v0 = bsum[t];
    lds[t] = v0;
    __syncthreads();
    for (int off = 1; off < 256; off <<= 1) {
        int v = (t >= off) ? lds[t - off] : 0;
        __syncthreads();
        lds[t] += v;
        __syncthreads();
    }
    boff[t] = lds[t] - v0;          // exclusive
    if (t == 255) rowptr[NN] = lds[255];
}
__global__ void scan_pass3(const int* __restrict__ deg, const int* __restrict__ boff,
                           int* __restrict__ rowptr, int* __restrict__ cursor) {
    __shared__ int lds[256];
    int b = blockIdx.x, t = threadIdx.x;
    int i = b * SCHUNK + t;
    int d = (t < SCHUNK && i < NN) ? deg[i] : 0;
    lds[t] = d;
    __syncthreads();
    for (int off = 1; off < 256; off <<= 1) {
        int v = (t >= off) ? lds[t - off] : 0;
        __syncthreads();
        lds[t] += v;
        __syncthreads();
    }
    if (t < SCHUNK && i < NN) {
        int excl = lds[t] - d + boff[b];
        rowptr[i] = excl;
        cursor[i] = excl;
    }
}
// edges + self-loops in one dispatch (intra-node order is irrelevant to softmax)
__global__ void scatter_all(const int* __restrict__ src, const int* __restrict__ dst,
                            int* __restrict__ cursor, int* __restrict__ colsrc) {
    int e = blockIdx.x * blockDim.x + threadIdx.x;
    if (e < NE) {
        int pos = atomicAdd(&cursor[dst[e]], 1);
        colsrc[pos] = src[e];
    } else if (e < NE + NN) {
        int n = e - NE;
        int pos = atomicAdd(&cursor[n], 1);
        colsrc[pos] = n;
    }
}

// ---------------- pass A: softmax-aggregate xbn -> z[n, 32*CP] (bf16) ----------------
template <int CIN, int CP>
__global__ __launch_bounds__(256) void agg_x(const unsigned short* __restrict__ xbn,
                                             const float* __restrict__ S,
                                             const int* __restrict__ rowptr,
                                             const int* __restrict__ colsrc,
                                             int n0, unsigned short* __restrict__ z) {
    constexpr int BS = 256, CH = 32, J = CP / 8;   // J = 16,12,6,2
    constexpr bool V4 = (J % 4 == 0);
    constexpr int NACC = V4 ? (J / 4) : (J / 2);
    __shared__ float x_lds[CH * CP];
    __shared__ float w_lds[CH * 32];
    __shared__ int cs_lds[CH];
    __shared__ float sdst[32], m_lds[32], d_lds[32], r_lds[32];
    __shared__ float red[8][32];

    int n = n0 + blockIdx.x;
    int tid = threadIdx.x;
    int start = rowptr[n], end = rowptr[n + 1];
    if (tid < 32) {
        sdst[tid] = S[(size_t)n * 64 + 32 + tid];
        m_lds[tid] = -INFINITY;
        d_lds[tid] = 0.f;
    }
    const int h = tid & 31, g = tid >> 5;
    const int cbase = g * J;
    f32x4 acc4[V4 ? NACC : 1];
    floatx2 acc2[V4 ? 1 : NACC];
    if constexpr (V4) {
#pragma unroll
        for (int j = 0; j < NACC; ++j) acc4[j] = f32x4{0.f, 0.f, 0.f, 0.f};
    } else {
#pragma unroll
        for (int j = 0; j < NACC; ++j) acc2[j] = floatx2{0.f, 0.f};
    }

    for (int chunk = start; chunk < end; chunk += CH) {
        int ce = min(CH, end - chunk);
        int ce32 = ce * 32;
        if (tid < 32 && tid < ce) cs_lds[tid] = colsrc[chunk + tid];
        __syncthreads();

        float lreg[4];
        float pmx = -INFINITY;
#pragma unroll
        for (int p = 0; p < 4; ++p) {
            int idx = p * 256 + tid;
            lreg[p] = -INFINITY;
            if (idx < ce32) {
                int e = idx >> 5;
                float l = S[(size_t)cs_lds[e] * 64 + h] + sdst[h];
                l = l > 0.f ? l : 0.2f * l;
                lreg[p] = l;
                pmx = fmaxf(pmx, l);
            }
        }
        red[g][h] = pmx;
        for (int idx = tid; idx < ce * (CP / 2); idx += BS) {
            int e = idx / (CP / 2), c2 = idx % (CP / 2);
            unsigned int u =
                reinterpret_cast<const unsigned int*>(xbn)[(size_t)cs_lds[e] * (CP / 2) + c2];
            x_lds[e * CP + 2 * c2]     = __uint_as_float(u << 16);
            x_lds[e * CP + 2 * c2 + 1] = __uint_as_float(u & 0xFFFF0000u);
        }
        __syncthreads();
        if (tid < 32) {
            float cm = red[0][tid];
#pragma unroll
            for (int s2 = 1; s2 < 8; ++s2) cm = fmaxf(cm, red[s2][tid]);
            float oldm = m_lds[tid], newm = fmaxf(oldm, cm);
            r_lds[tid] = (oldm == -INFINITY) ? 0.f : __expf(oldm - newm);
            m_lds[tid] = newm;
        }
        __syncthreads();
        {
            float mh = m_lds[h];
            float ps = 0.f;
#pragma unroll
            for (int p = 0; p < 4; ++p) {
                int idx = p * 256 + tid;
                if (idx < ce32) {
                    float v = __expf(lreg[p] - mh);
                    w_lds[idx] = v;
                    ps += v;
                }
            }
            red[g][h] = ps;
        }
        __syncthreads();
        if (tid < 32) {
            float ss = 0.f;
#pragma unroll
            for (int s2 = 0; s2 < 8; ++s2) ss += red[s2][tid];
            d_lds[tid] = d_lds[tid] * r_lds[tid] + ss;
        }
        float rr = r_lds[h];
        if constexpr (V4) {
            f32x4 rr4 = {rr, rr, rr, rr};
#pragma unroll
            for (int j = 0; j < NACC; ++j) acc4[j] *= rr4;
            for (int e = 0; e < ce; ++e) {
                float w = w_lds[e * 32 + h];
                f32x4 w4 = {w, w, w, w};
                const f32x4* xv = reinterpret_cast<const f32x4*>(&x_lds[e * CP + cbase]);
#pragma unroll
                for (int j = 0; j < NACC; ++j) acc4[j] += w4 * xv[j];
            }
        } else {
            floatx2 rr2 = {rr, rr};
#pragma unroll
            for (int j = 0; j < NACC; ++j) acc2[j] *= rr2;
            for (int e = 0; e < ce; ++e) {
                float w = w_lds[e * 32 + h];
                floatx2 w2 = {w, w};
                const floatx2* xv = reinterpret_cast<const floatx2*>(&x_lds[e * CP + cbase]);
#pragma unroll
                for (int j = 0; j < NACC; ++j) acc2[j] += w2 * xv[j];
            }
        }
    }
    __syncthreads();
    float dinv = 1.f / d_lds[h];
    unsigned int* zp = reinterpret_cast<unsigned int*>(
        z + (size_t)(n - n0) * (32 * CP) + h * CP + cbase);
    if constexpr (V4) {
#pragma unroll
        for (int j = 0; j < NACC; ++j) {
            zp[2 * j]     = (unsigned int)f2bf(acc4[j][0] * dinv)
                          | ((unsigned int)f2bf(acc4[j][1] * dinv) << 16);
            zp[2 * j + 1] = (unsigned int)f2bf(acc4[j][2] * dinv)
                          | ((unsigned int)f2bf(acc4[j][3] * dinv) << 16);
        }
    } else {
#pragma unroll
        for (int j = 0; j < NACC; ++j) {
            zp[j] = (unsigned int)f2bf(acc2[j][0] * dinv)
                  | ((unsigned int)f2bf(acc2[j][1] * dinv) << 16);
        }
    }
}

// ---------------- pass B: LDS-tiled MFMA GEMM ----------------
// FB=false: K-split copies into pbuf (part blockIdx.y), reduced by reduce_parts.
// FB=true (KS must be 1): bias+leaky fused, store direct to xout — no extra dispatch.
template <int NT, int KP, int KS, bool FB>
__global__ __launch_bounds__(256) void gemm_z_t(const unsigned short* __restrict__ z,
                                                const unsigned short* __restrict__ Wt,
                                                float* __restrict__ obuf,
                                                const float* __restrict__ bias,
                                                int n0, int COUT) {
    constexpr int NP = NT * 16;
    constexpr int KSEG = KP / KS;       // multiple of 64
    constexpr int NC = KSEG / 64;
    constexpr int MT = 128;
    __shared__ unsigned short Abuf[2][MT * 64];
    __shared__ unsigned short Bbuf[2][NP * 64];

    const int m0 = blockIdx.x * MT;
    const int kbeg = blockIdx.y * KSEG;
    const int tid = threadIdx.x;
    const int wv = tid >> 6;
    const int lane = tid & 63;
    const int mm = lane & 15, quad = lane >> 4;

    auto stage = [&](int buf, int kk) {
#pragma unroll
        for (int it = 0; it < 4; ++it) {
            int gi = it * 256 + tid;
            int row = gi >> 3, gc = gi & 7;
            int srow = m0 + row;
            if (srow > NSLAB - 1) srow = NSLAB - 1;
            const unsigned short* src = z + (size_t)srow * KP + kk + gc * 8;
            unsigned short* dst = &Abuf[buf][(size_t)(it * 256 + wv * 64) * 8];
            load_lds16(src, dst);
        }
#pragma unroll
        for (int it = 0; it < (NP * 8 + 255) / 256; ++it) {
            int gi = it * 256 + tid;
            if (gi < NP * 8) {
                int row = gi >> 3, gc = gi & 7;
                const unsigned short* src = Wt + (size_t)row * KP + kk + gc * 8;
                unsigned short* dst = &Bbuf[buf][(size_t)(it * 256 + wv * 64) * 8];
                load_lds16(src, dst);
            }
        }
    };

    f32x4 acc[2][NT];
#pragma unroll
    for (int f = 0; f < 2; ++f)
#pragma unroll
        for (int t = 0; t < NT; ++t) acc[f][t] = f32x4{0.f, 0.f, 0.f, 0.f};

    stage(0, kbeg);
    for (int c = 0; c < NC; ++c) {
        asm volatile("s_waitcnt vmcnt(0)" ::: "memory");
        __syncthreads();
        int cur = c & 1;
        if (c + 1 < NC) stage(cur ^ 1, kbeg + (c + 1) * 64);
        const unsigned short* Ab = Abuf[cur];
        const unsigned short* Bb = Bbuf[cur];
#pragma unroll
        for (int hh = 0; hh < 2; ++hh) {
            bf16x8 a0 = *reinterpret_cast<const bf16x8*>(&Ab[(wv * 32 + mm) * 64 + hh * 32 + quad * 8]);
            bf16x8 a1 = *reinterpret_cast<const bf16x8*>(&Ab[(wv * 32 + 16 + mm) * 64 + hh * 32 + quad * 8]);
#pragma unroll
            for (int t = 0; t < NT; ++t) {
                bf16x8 b = *reinterpret_cast<const bf16x8*>(&Bb[(t * 16 + mm) * 64 + hh * 32 + quad * 8]);
                acc[0][t] = __builtin_amdgcn_mfma_f32_16x16x32_bf16(a0, b, acc[0][t], 0, 0, 0);
                acc[1][t] = __builtin_amdgcn_mfma_f32_16x16x32_bf16(a1, b, acc[1][t], 0, 0, 0);
            }
        }
        __syncthreads();
    }

    int row0 = quad * 4;
    if constexpr (FB) {
#pragma unroll
        for (int f = 0; f < 2; ++f) {
#pragma unroll
            for (int t = 0; t < NT; ++t) {
                int cc = t * 16 + mm;
#pragma unroll
                for (int r = 0; r < 4; ++r) {
                    int m = m0 + wv * 32 + f * 16 + row0 + r;
                    if (m < NSLAB && cc < COUT) {
                        float v = acc[f][t][r] + bias[cc];
                        v = v > 0.f ? v : 0.01f * v;
                        obuf[(size_t)(n0 + m) * COUT + cc] = v;
                    }
                }
            }
        }
    } else {
        float* pb = obuf + (size_t)blockIdx.y * MPAD * NP;
#pragma unroll
        for (int f = 0; f < 2; ++f) {
#pragma unroll
            for (int t = 0; t < NT; ++t) {
                int cc = t * 16 + mm;
#pragma unroll
                for (int r = 0; r < 4; ++r) {
                    int m = m0 + wv * 32 + f * 16 + row0 + r;
                    pb[(size_t)m * NP + cc] = acc[f][t][r];
                }
            }
        }
    }
}

// reduce K-split partials + bias + leaky 0.01 -> xout
__global__ void reduce_parts(const float* __restrict__ pbuf, int KS, int NPAD, int COUT,
                             const float* __restrict__ bias, int n0,
                             float* __restrict__ xout) {
    int idx = blockIdx.x * blockDim.x + threadIdx.x;
    if (idx >= NSLAB * NPAD) return;
    int m = idx / NPAD, c = idx % NPAD;
    if (c >= COUT) return;
    float s = 0.f;
    for (int p = 0; p < KS; ++p) s += pbuf[(size_t)p * MPAD * NPAD + (size_t)m * NPAD + c];
    float v = s + bias[c];
    v = v > 0.f ? v : 0.01f * v;
    xout[(size_t)(n0 + m) * COUT + c] = v;
}

// ---------------- fused mean-pool + FC + sigmoid ----------------
__global__ __launch_bounds__(64) void pool_head(const float* __restrict__ x4,
                                                const int* __restrict__ batch,
                                                const float* __restrict__ cond,
                                                const float* __restrict__ fcW,
                                                const float* __restrict__ fcb,
                                                float* __restrict__ out) {
    int g = blockIdx.x;
    int lane = threadIdx.x;
    int lo = 0, hi = NN;
    while (lo < hi) { int mid = (lo + hi) >> 1; if (batch[mid] < g) lo = mid + 1; else hi = mid; }
    int lo2 = lo, hi2 = NN;
    while (lo2 < hi2) { int mid = (lo2 + hi2) >> 1; if (batch[mid] < g + 1) lo2 = mid + 1; else hi2 = mid; }
    int beg = lo, end = lo2;

    float s[5] = {0.f, 0.f, 0.f, 0.f, 0.f};
    for (int n = beg + lane; n < end; n += 64) {
#pragma unroll
        for (int c = 0; c < 5; ++c) s[c] += x4[(size_t)n * 5 + c];
    }
    float cz = 0.f;
    if (lane < 100) cz = cond[lane] * fcW[5 + lane];
    if (lane + 64 < 100) cz += cond[lane + 64] * fcW[5 + lane + 64];
#pragma unroll
    for (int off = 32; off > 0; off >>= 1) {
#pragma unroll
        for (int c = 0; c < 5; ++c) s[c] += __shfl_down(s[c], off, 64);
        cz += __shfl_down(cz, off, 64);
    }
    if (lane == 0) {
        float cnt = fmaxf((float)(end - beg), 1.f);
        float zv = fcb[0] + cz;
#pragma unroll
        for (int c = 0; c < 5; ++c) zv += (s[c] / cnt) * fcW[c];
        out[g] = 1.f / (1.f + __expf(-zv));
    }
}

// ---------------- per-layer driver ----------------
struct LayerBufs {
    float* partial; float* scale; float* shift; float* Wf;
    unsigned short* Wft;
    unsigned short* xbn; unsigned short* Wt; unsigned short* zbuf;
    float* Sbuf; float* pbuf; const int* rowptr; const int* colsrc;
};

template <int CIN, int CP, int COUT, int NP, int NT, int KS>
static void run_layer(const float* xin, const float* W, const float* As_, const float* Ad_,
                      const float* Bv, const float* G, const float* Be,
                      float* xout, const LayerBufs& B, hipStream_t stream) {
    constexpr int KP = 32 * CP;
    constexpr int NPAD = NT * 16;
    bn_partial<<<256, 128, 0, stream>>>(xin, NN, CIN, B.partial);
    bn_finalize<<<1, 128, 0, stream>>>(B.partial, 256, CIN, (float)NN, G, Be, B.scale, B.shift);
    bn_apply<CIN, CP><<<(NN * CP + 255) / 256, 256, 0, stream>>>(xin, B.scale, B.shift, B.xbn);
    prep_weights<<<CP + NP, 256, 0, stream>>>(W, As_, Ad_, CIN, CP, COUT, B.Wf, B.Wft, B.Wt);
    if constexpr (CP >= 64) {
        gemm_s<CP><<<NN / 64, 256, 0, stream>>>(B.xbn, B.Wft, B.Sbuf);   // r15 fix: <CP> not <KP>
    } else {
        gemm_bn<<<dim3(1, NN / 64), 256, 0, stream>>>(xin, B.Wf, B.scale, B.shift, CIN, 64, B.Sbuf);
    }
    for (int s = 0; s < 2; ++s) {
        int n0 = s * NSLAB;
        agg_x<CIN, CP><<<NSLAB, 256, 0, stream>>>(B.xbn, B.Sbuf, B.rowptr, B.colsrc, n0, B.zbuf);
        if constexpr (KS > 1) {
            gemm_z_t<NT, KP, KS, false><<<dim3(MPAD / 128, KS), 256, 0, stream>>>(
                B.zbuf, B.Wt, B.pbuf, nullptr, n0, COUT);
            reduce_parts<<<(NSLAB * NPAD + 255) / 256, 256, 0, stream>>>(
                B.pbuf, KS, NPAD, COUT, Bv, n0, xout);
        } else {
            gemm_z_t<NT, KP, 1, true><<<dim3(MPAD / 128, 1), 256, 0, stream>>>(
                B.zbuf, B.Wt, xout, Bv, n0, COUT);
        }
    }
}

extern "C" void kernel_launch(void* const* d_in, const int* in_sizes, int n_in,
                              void* d_out, int out_size, void* d_ws, size_t ws_size,
                              hipStream_t stream) {
    (void)in_sizes; (void)n_in; (void)out_size;
    const float* x     = (const float*)d_in[0];
    const int*   ei    = (const int*)d_in[1];
    const int*   batch = (const int*)d_in[2];
    const float* cond  = (const float*)d_in[3];
    const float* W[4]  = {(const float*)d_in[4],  (const float*)d_in[8],
                          (const float*)d_in[12], (const float*)d_in[16]};
    const float* Asp[4] = {(const float*)d_in[5],  (const float*)d_in[9],
                           (const float*)d_in[13], (const float*)d_in[17]};
    const float* Adp[4] = {(const float*)d_in[6],  (const float*)d_in[10],
                           (const float*)d_in[14], (const float*)d_in[18]};
    const float* Bv[4]  = {(const float*)d_in[7],  (const float*)d_in[11],
                           (const float*)d_in[15], (const float*)d_in[19]};
    const float* G[4]   = {(const float*)d_in[20], (const float*)d_in[22],
                           (const float*)d_in[24], (const float*)d_in[26]};
    const float* Be[4]  = {(const float*)d_in[21], (const float*)d_in[23],
                           (const float*)d_in[25], (const float*)d_in[27]};
    const float* fcW = (const float*)d_in[30];
    const float* fcb = (const float*)d_in[31];
    float* out = (float*)d_out;

    char* base = (char*)d_ws;
    size_t off = 0;
    auto alloc = [&](size_t b) {
        size_t o = off;
        off += (b + 255) & ~(size_t)255;
        return (void*)(base + o);
    };
    unsigned short* zbuf = (unsigned short*)alloc((size_t)NSLAB * 4096 * 2);
    unsigned short* xbn  = (unsigned short*)alloc((size_t)NN * 128 * 2);
    unsigned short* Wt   = (unsigned short*)alloc((size_t)96 * 4096 * 2);
    unsigned short* Wft  = (unsigned short*)alloc((size_t)64 * 128 * 2);
    float* pbuf    = (float*)alloc((size_t)2 * MPAD * 96 * 4);
    float* xbuf    = (float*)alloc((size_t)NN * 90 * 4);
    float* Sbuf    = (float*)alloc((size_t)NN * 64 * 4);
    float* partial = (float*)alloc((size_t)256 * 2 * 128 * 4);
    float* scale   = (float*)alloc(128 * 4);
    float* shift   = (float*)alloc(128 * 4);
    float* Wf      = (float*)alloc(128 * 64 * 4);
    int* deg     = (int*)alloc((size_t)NN * 4);
    int* rowptr  = (int*)alloc((size_t)(NN + 1) * 4);
    int* cursor  = (int*)alloc((size_t)NN * 4);
    int* colsrc  = (int*)alloc((size_t)(NE + NN) * 4);
    int* bsum    = (int*)alloc((size_t)SCB * 4);
    int* boff    = (int*)alloc((size_t)SCB * 4);
    if (off > ws_size) return;

    const int* srcp = ei;
    const int* dstp = ei + NE;

    // CSR by dst (hierarchical scan)
    deg_init<<<(NN + 255) / 256, 256, 0, stream>>>(deg);
    count_kernel<<<(NE + 255) / 256, 256, 0, stream>>>(dstp, deg);
    scan_pass1<<<SCB, 256, 0, stream>>>(deg, bsum);
    scan_pass2<<<1, 256, 0, stream>>>(bsum, boff, rowptr);
    scan_pass3<<<SCB, 256, 0, stream>>>(deg, boff, rowptr, cursor);
    scatter_all<<<(NE + NN + 255) / 256, 256, 0, stream>>>(srcp, dstp, cursor, colsrc);

    LayerBufs B{partial, scale, shift, Wf, Wft, xbn, Wt, zbuf, Sbuf, pbuf, rowptr, colsrc};

    // L1: 128 -> 90 ; L2: 90 -> 45 ; L3: 45 -> 15 ; L4: 15 -> 5
    run_layer<128, 128, 90, 96, 6, 2>(x,    W[0], Asp[0], Adp[0], Bv[0], G[0], Be[0], xbuf, B, stream);
    run_layer< 90,  96, 45, 48, 3, 2>(xbuf, W[1], Asp[1], Adp[1], Bv[1], G[1], Be[1], xbuf, B, stream);
    run_layer< 45,  48, 15, 16, 1, 1>(xbuf, W[2], Asp[2], Adp[2], Bv[2], G[2], Be[2], xbuf, B, stream);
    run_layer< 15,  16,  5, 16, 1, 1>(xbuf, W[3], Asp[3], Adp[3], Bv[3], G[3], Be[3], xbuf, B, stream);

    pool_head<<<256, 64, 0, stream>>>(xbuf, batch, cond, fcW, fcb, out);
}